// Round 4
// baseline (40453.842 us; speedup 1.0000x reference)
//
#include <hip/hip_runtime.h>
#include <stdint.h>

#define T_ 512
#define B_ 64
#define IN_ 512
#define H_ 1024
#define RB 16
#define NCG 32
#define RING 8
#define LNEPS 1e-5f

typedef __attribute__((ext_vector_type(8))) short s16x8;
typedef __attribute__((ext_vector_type(4))) float f32x4;
typedef __attribute__((ext_vector_type(4))) float float4v;
typedef unsigned short ushort_t;

__device__ __forceinline__ unsigned short f2bf(float f) {
  unsigned u = __builtin_bit_cast(unsigned, f);
  return (unsigned short)((u + 0x7FFFu + ((u >> 16) & 1u)) >> 16);
}
__device__ __forceinline__ float bf2f(unsigned short h) {
  return __builtin_bit_cast(float, (unsigned)h << 16);
}
__device__ __forceinline__ float tanh_fast(float y) {
  y = fminf(15.f, fmaxf(-15.f, y));
  float t = __expf(2.f * y);
  return (t - 1.f) / (t + 1.f);
}
struct HiLo { short hi, lo; };
__device__ __forceinline__ HiLo split1(float v) {
  HiLo r;
  unsigned short h = f2bf(v);
  r.hi = (short)h;
  r.lo = (short)f2bf(v - bf2f(h));
  return r;
}
__device__ __forceinline__ void ldw8s(const float* p, s16x8& hi, s16x8& lo) {
  float4v a = *(const float4v*)p;
  float4v b = *(const float4v*)(p + 4);
#pragma unroll
  for (int i = 0; i < 4; ++i) {
    HiLo x = split1(a[i]); hi[i] = x.hi; lo[i] = x.lo;
    HiLo y = split1(b[i]); hi[4 + i] = y.hi; lo[4 + i] = y.lo;
  }
}

// relaxed poll: no per-iteration buffer_inv; every 64th poll is an RMW (staleness insurance)
__device__ __forceinline__ void spinR(int* p, int target) {
  int n = 0;
  while (true) {
    int v = ((n & 63) == 63)
        ? __hip_atomic_fetch_add(p, 0, __ATOMIC_RELAXED, __HIP_MEMORY_SCOPE_AGENT)
        : __hip_atomic_load(p, __ATOMIC_RELAXED, __HIP_MEMORY_SCOPE_AGENT);
    if (v >= target) return;
    __builtin_amdgcn_s_sleep(1);
    if (++n > 4000000) return;  // safety: wrong data instead of hang
  }
}
__device__ __forceinline__ void addrel(int* p) {
  __hip_atomic_fetch_add(p, 1, __ATOMIC_RELEASE, __HIP_MEMORY_SCOPE_AGENT);
}
#define ACQ() __builtin_amdgcn_fence(__ATOMIC_ACQUIRE, "agent")

// swizzled LDS ushort index: 16B chunk XOR'd with row low bits (breaks read/write conflicts)
__device__ __forceinline__ int chix(int r, int c) {
  return r * 1032 + ((((c >> 3) ^ (r & 3))) << 3) + (c & 7);
}

// ---- staging (512 threads; thread: r=tid>>5 in 0..15, k=tid&31 owns cols 32k..32k+31) ----
__device__ __forceinline__ void stageF32(const float* src, ushort_t* dh, ushort_t* dl, int tid) {
  int r = tid >> 5, k = tid & 31, c0 = k * 32;
  const float* p = src + (size_t)r * H_ + c0;
  float f[32];
#pragma unroll
  for (int q = 0; q < 8; ++q) {
    float4v v = *(const float4v*)(p + q * 4);
#pragma unroll
    for (int i = 0; i < 4; ++i) f[q * 4 + i] = v[i];
  }
#pragma unroll
  for (int i = 0; i < 4; ++i) {
    int q = (i + k) & 3;  // rotated write order: 16-way -> 8-way bank conflict
    s16x8 hi, lo;
#pragma unroll
    for (int j = 0; j < 8; ++j) { HiLo x = split1(f[q * 8 + j]); hi[j] = x.hi; lo[j] = x.lo; }
    int ix = chix(r, c0 + q * 8);
    *(s16x8*)&dh[ix] = hi; *(s16x8*)&dl[ix] = lo;
  }
}
__device__ __forceinline__ void stageX(const float* src, ushort_t* dh, ushort_t* dl, int tid) {
  int r = tid >> 5, k = tid & 31, c0 = k * 16;
  const float* p = src + (size_t)r * IN_ + c0;
  float f[16];
#pragma unroll
  for (int q = 0; q < 4; ++q) {
    float4v v = *(const float4v*)(p + q * 4);
#pragma unroll
    for (int i = 0; i < 4; ++i) f[q * 4 + i] = v[i];
  }
#pragma unroll
  for (int i = 0; i < 2; ++i) {
    int q = (i + k) & 1;
    s16x8 hi, lo;
#pragma unroll
    for (int j = 0; j < 8; ++j) { HiLo x = split1(f[q * 8 + j]); hi[j] = x.hi; lo[j] = x.lo; }
    int ix = chix(r, c0 + q * 8);
    *(s16x8*)&dh[ix] = hi; *(s16x8*)&dl[ix] = lo;
  }
}
// fp32 pre rows -> LN+tanh -> split LDS; if cgsel>=0, thread k==cgsel writes fp32 rows to gA (and gB)
// lnw/lnb are LDS arrays in PERMUTED layout: logical 32k+c stored at 32k+((c+k)&31)
__device__ __forceinline__ void stageLT(const float* src, ushort_t* dh, ushort_t* dl,
                                        const float* lnw, const float* lnb, int tid,
                                        int cgsel, float* gA, float* gB) {
  int r = tid >> 5, k = tid & 31, c0 = k * 32;
  const float* p = src + (size_t)r * H_ + c0;
  float f[32];
  float s = 0.f, ss = 0.f;
#pragma unroll
  for (int q = 0; q < 8; ++q) {
    float4v v = *(const float4v*)(p + q * 4);
#pragma unroll
    for (int i = 0; i < 4; ++i) { float x = v[i]; f[q * 4 + i] = x; s += x; ss += x * x; }
  }
#pragma unroll
  for (int m = 1; m <= 16; m <<= 1) { s += __shfl_xor(s, m, 64); ss += __shfl_xor(ss, m, 64); }
  float mu = s * (1.f / H_);
  float var = ss * (1.f / H_) - mu * mu;
  float rs = rsqrtf(var + LNEPS);
#pragma unroll
  for (int c = 0; c < 32; ++c) {
    int pi = c0 + ((c + k) & 31);  // permuted, conflict-free LN param read
    float y = (f[(c + k) & 31] - mu) * rs;
    // note: (c+k)&31 is runtime for f[] -> avoid; instead read param for logical col c:
    (void)pi; (void)y;
  }
  // conflict-free LN param reads with STATIC f index: lane k reads logical col c via perm layout
#pragma unroll
  for (int c = 0; c < 32; ++c) {
    float w = lnw[c0 + ((c + k) & 31)];  // logical col c0+c (perm layout)
    float b = lnb[c0 + ((c + k) & 31)];
    // perm stores logical (32k + cc) at physical (32k + ((cc+k)&31)); reading physical
    // (32k + ((c+k)&31)) returns logical col (32k + c). f index stays the static c.
    float y = (f[c] - mu) * rs * w + b;
    f[c] = tanh_fast(y);
  }
  if (cgsel >= 0 && k == cgsel) {
    float* pa = gA + (size_t)r * H_ + c0;
#pragma unroll
    for (int q = 0; q < 8; ++q) *(float4v*)(pa + q * 4) = *(const float4v*)&f[q * 4];
    if (gB) {
      float* pb = gB + (size_t)r * H_ + c0;
#pragma unroll
      for (int q = 0; q < 8; ++q) *(float4v*)(pb + q * 4) = *(const float4v*)&f[q * 4];
    }
  }
#pragma unroll
  for (int i = 0; i < 4; ++i) {
    int q = (i + k) & 3;
    s16x8 hi, lo;
#pragma unroll
    for (int j = 0; j < 8; ++j) { HiLo x = split1(f[q * 8 + j]); hi[j] = x.hi; lo[j] = x.lo; }
    int ix = chix(r, c0 + q * 8);
    *(s16x8*)&dh[ix] = hi; *(s16x8*)&dl[ix] = lo;
  }
}

#define MFMA(a, b, c) __builtin_amdgcn_mfma_f32_16x16x32_bf16(a, b, c, 0, 0, 0)
#define AF(buf, idx) (*(const s16x8*)&buf[chix(lane & 15, (idx) + kb8)])

__global__ __launch_bounds__(512, 1) void rnn_persist(
    const float* __restrict__ input, const float* __restrict__ hidden,
    const float* __restrict__ W_ih0, const float* __restrict__ W_hh0,
    const float* __restrict__ b_ih0, const float* __restrict__ b_hh0,
    const float* __restrict__ ln_w0, const float* __restrict__ ln_b0,
    const float* __restrict__ W_ih1, const float* __restrict__ W_hh1,
    const float* __restrict__ b_ih1, const float* __restrict__ b_hh1,
    const float* __restrict__ ln_w1, const float* __restrict__ ln_b1,
    float* gout, float* pre0, float* pre1, int* flag0, int* flag1) {
  __shared__ ushort_t sAh[16 * 1032];
  __shared__ ushort_t sAl[16 * 1032];
  __shared__ float slnw0[1024], slnb0[1024];
  __shared__ float slnw1[1024], slnb1[1024];
  __shared__ float sacc[2][3][16][16];

  const int tid = threadIdx.x;
  const int lane = tid & 63;
  const int w = tid >> 6;
  const int colt = w & 1, kh = w >> 1;  // 2 col-tiles x 4 K-quarters
  const int blk = blockIdx.x;
  const int layer = blk >> 7;
  const int id = blk & 127;
  const int rg = id >> 5, cg = id & 31;
  const int rowbase = rg * RB;
  const int cgl = cg * 32 + colt * 16 + (lane & 15);
  const int kb8 = (lane >> 4) * 8;
  const int l15 = lane & 15;

  // LN params in permuted layout (conflict-free reads in stageLT)
  for (int i = tid; i < H_; i += 512) {
    int pi = (i & ~31) | ((i + (i >> 5)) & 31);
    slnw0[pi] = ln_w0[i]; slnb0[pi] = ln_b0[i];
    slnw1[pi] = ln_w1[i]; slnb1[pi] = ln_b1[i];
  }

  float bias = 0.f;

  if (layer == 0) {
    s16x8 WhiX[4], WloX[4], WhiH[8], WloH[8];
#pragma unroll
    for (int s = 0; s < 4; ++s)
      ldw8s(W_ih0 + (size_t)cgl * IN_ + kh * 128 + s * 32 + kb8, WhiX[s], WloX[s]);
#pragma unroll
    for (int s = 0; s < 8; ++s)
      ldw8s(W_hh0 + (size_t)cgl * H_ + kh * 256 + s * 32 + kb8, WhiH[s], WloH[s]);
    if (kh == 0) bias = b_ih0[cgl] + b_hh0[cgl];
    __syncthreads();

    for (int t = 0; t < T_; ++t) {
      stageX(input + ((size_t)t * B_ + rowbase) * IN_, sAh, sAl, tid);
      __syncthreads();
      f32x4 aP = (kh == 0) ? (f32x4){bias, bias, bias, bias} : (f32x4){0.f, 0.f, 0.f, 0.f};
      f32x4 aQ = {0.f, 0.f, 0.f, 0.f}, aR = {0.f, 0.f, 0.f, 0.f};
#pragma unroll
      for (int s = 0; s < 4; ++s) {
        s16x8 ah = AF(sAh, kh * 128 + s * 32), al = AF(sAl, kh * 128 + s * 32);
        aP = MFMA(ah, WhiX[s], aP); aQ = MFMA(ah, WloX[s], aQ); aR = MFMA(al, WhiX[s], aR);
      }
      if (tid == 0 && t > 0) spinR(&flag0[(t - 1) * 4 + rg], NCG);
      if (tid == 64 && t >= RING) spinR(&flag1[(t - RING) * 4 + rg], NCG);
      __syncthreads();
      ACQ();  // one L2-inv per step (per wave), not per poll
      if (t == 0) stageF32(hidden + (size_t)rowbase * H_, sAh, sAl, tid);
      else stageLT(pre0 + ((size_t)((t - 1) & 7) * B_ + rowbase) * H_, sAh, sAl,
                   slnw0, slnb0, tid, -1, nullptr, nullptr);
      __syncthreads();
#pragma unroll
      for (int s = 0; s < 8; ++s) {
        s16x8 ah = AF(sAh, kh * 256 + s * 32), al = AF(sAl, kh * 256 + s * 32);
        aP = MFMA(ah, WhiH[s], aP); aQ = MFMA(ah, WloH[s], aQ); aR = MFMA(al, WhiH[s], aR);
      }
      f32x4 sum = aP + aQ + aR;
      if (kh > 0) {
#pragma unroll
        for (int j = 0; j < 4; ++j) sacc[colt][kh - 1][(lane >> 4) * 4 + j][l15] = sum[j];
      }
      __syncthreads();
      if (kh == 0) {
        float* dst = pre0 + ((size_t)(t & 7) * B_ + rowbase) * H_;
#pragma unroll
        for (int j = 0; j < 4; ++j) {
          int row = (lane >> 4) * 4 + j;
          float v = sum[j] + sacc[colt][0][row][l15] + sacc[colt][1][row][l15] +
                    sacc[colt][2][row][l15];
          dst[(size_t)row * H_ + cgl] = v;
        }
      }
      __syncthreads();  // drains pre0 stores (compiler vmcnt(0) before barrier)
      if (tid == 0) addrel(&flag0[t * 4 + rg]);
    }
    // epilogue: h_fin[0] slice
    if (tid == 0) spinR(&flag0[(T_ - 1) * 4 + rg], NCG);
    __syncthreads();
    ACQ();
    stageLT(pre0 + ((size_t)((T_ - 1) & 7) * B_ + rowbase) * H_, sAh, sAl, slnw0, slnb0,
            tid, cg, gout + (size_t)T_ * B_ * H_ + (size_t)rowbase * H_, nullptr);
  } else {
    s16x8 WhiA[8], WloA[8], WhiB[8], WloB[8];
#pragma unroll
    for (int s = 0; s < 8; ++s)
      ldw8s(W_hh1 + (size_t)cgl * H_ + kh * 256 + s * 32 + kb8, WhiA[s], WloA[s]);
#pragma unroll
    for (int s = 0; s < 8; ++s)
      ldw8s(W_ih1 + (size_t)cgl * H_ + kh * 256 + s * 32 + kb8, WhiB[s], WloB[s]);
    if (kh == 0) bias = b_ih1[cgl] + b_hh1[cgl];
    __syncthreads();

    for (int t = 0; t < T_; ++t) {
      if (tid == 0) spinR(&flag0[t * 4 + rg], NCG);
      if (tid == 64 && t > 0) spinR(&flag1[(t - 1) * 4 + rg], NCG);
      __syncthreads();
      ACQ();
      // h0[t] part first (flag0[t] is pre-satisfied in steady state: L0 runs ahead)
      stageLT(pre0 + ((size_t)(t & 7) * B_ + rowbase) * H_, sAh, sAl,
              slnw0, slnb0, tid, -1, nullptr, nullptr);
      __syncthreads();
      f32x4 aP = (kh == 0) ? (f32x4){bias, bias, bias, bias} : (f32x4){0.f, 0.f, 0.f, 0.f};
      f32x4 aQ = {0.f, 0.f, 0.f, 0.f}, aR = {0.f, 0.f, 0.f, 0.f};
#pragma unroll
      for (int s = 0; s < 8; ++s) {
        s16x8 ah = AF(sAh, kh * 256 + s * 32), al = AF(sAl, kh * 256 + s * 32);
        aP = MFMA(ah, WhiB[s], aP); aQ = MFMA(ah, WloB[s], aQ); aR = MFMA(al, WhiB[s], aR);
      }
      __syncthreads();  // LDS reads retired before overwrite
      // h1[t-1]: consumer-side LN1+tanh; also writes gout[t-1] slice
      if (t == 0) stageF32(hidden + (size_t)B_ * H_ + (size_t)rowbase * H_, sAh, sAl, tid);
      else stageLT(pre1 + ((size_t)((t - 1) & 7) * B_ + rowbase) * H_, sAh, sAl,
                   slnw1, slnb1, tid, cg,
                   gout + ((size_t)(t - 1) * B_ + rowbase) * H_, nullptr);
      __syncthreads();
#pragma unroll
      for (int s = 0; s < 8; ++s) {
        s16x8 ah = AF(sAh, kh * 256 + s * 32), al = AF(sAl, kh * 256 + s * 32);
        aP = MFMA(ah, WhiA[s], aP); aQ = MFMA(ah, WloA[s], aQ); aR = MFMA(al, WhiA[s], aR);
      }
      f32x4 sum = aP + aQ + aR;
      if (kh > 0) {
#pragma unroll
        for (int j = 0; j < 4; ++j) sacc[colt][kh - 1][(lane >> 4) * 4 + j][l15] = sum[j];
      }
      __syncthreads();
      if (kh == 0) {
        float* dst = pre1 + ((size_t)(t & 7) * B_ + rowbase) * H_;
#pragma unroll
        for (int j = 0; j < 4; ++j) {
          int row = (lane >> 4) * 4 + j;
          float v = sum[j] + sacc[colt][0][row][l15] + sacc[colt][1][row][l15] +
                    sacc[colt][2][row][l15];
          dst[(size_t)row * H_ + cgl] = v;
        }
      }
      __syncthreads();
      if (tid == 0) addrel(&flag1[t * 4 + rg]);
    }
    // epilogue: gout[T-1] + h_fin[1] slices
    if (tid == 0) spinR(&flag1[(T_ - 1) * 4 + rg], NCG);
    __syncthreads();
    ACQ();
    stageLT(pre1 + ((size_t)((T_ - 1) & 7) * B_ + rowbase) * H_, sAh, sAl, slnw1, slnb1,
            tid, cg, gout + ((size_t)(T_ - 1) * B_ + rowbase) * H_,
            gout + (size_t)T_ * B_ * H_ + (size_t)B_ * H_ + (size_t)rowbase * H_);
  }
}

extern "C" void kernel_launch(void* const* d_in, const int* in_sizes, int n_in,
                              void* d_out, int out_size, void* d_ws, size_t ws_size,
                              hipStream_t stream) {
  const float* input = (const float*)d_in[0];
  const float* hidden = (const float*)d_in[1];
  const float* W_ih0 = (const float*)d_in[2];
  const float* W_hh0 = (const float*)d_in[3];
  const float* b_ih0 = (const float*)d_in[4];
  const float* b_hh0 = (const float*)d_in[5];
  const float* ln_w0 = (const float*)d_in[6];
  const float* ln_b0 = (const float*)d_in[7];
  const float* W_ih1 = (const float*)d_in[8];
  const float* W_hh1 = (const float*)d_in[9];
  const float* b_ih1 = (const float*)d_in[10];
  const float* b_hh1 = (const float*)d_in[11];
  const float* ln_w1 = (const float*)d_in[12];
  const float* ln_b1 = (const float*)d_in[13];
  float* gout = (float*)d_out;

  char* ws = (char*)d_ws;
  float* pre0 = (float*)ws;                     // 8*64*1024*4 = 2 MB
  float* pre1 = (float*)(ws + (2u << 20));      // 2 MB
  char* ctrl = ws + (4u << 20);
  int* flag0 = (int*)ctrl;                      // 8 KB
  int* flag1 = (int*)(ctrl + 8192);             // 8 KB

  (void)hipMemsetAsync(ctrl, 0, 16384, stream);
  hipLaunchKernelGGL(rnn_persist, dim3(256), dim3(512), 0, stream,
                     input, hidden, W_ih0, W_hh0, b_ih0, b_hh0, ln_w0, ln_b0,
                     W_ih1, W_hh1, b_ih1, b_hh1, ln_w1, ln_b1,
                     gout, pre0, pre1, flag0, flag1);
}

// Round 5
// 34132.556 us; speedup vs baseline: 1.1852x; 1.1852x over previous
//
#include <hip/hip_runtime.h>
#include <stdint.h>

#define T_ 512
#define B_ 64
#define IN_ 512
#define H_ 1024
#define RB 16
#define NCG 32
#define RING 8
#define LNEPS 1e-5f

typedef __attribute__((ext_vector_type(8))) short s16x8;
typedef __attribute__((ext_vector_type(4))) float f32x4;
typedef __attribute__((ext_vector_type(4))) float float4v;
typedef unsigned short ushort_t;

__device__ __forceinline__ unsigned short f2bf(float f) {
  unsigned u = __builtin_bit_cast(unsigned, f);
  return (unsigned short)((u + 0x7FFFu + ((u >> 16) & 1u)) >> 16);
}
__device__ __forceinline__ float bf2f(unsigned short h) {
  return __builtin_bit_cast(float, (unsigned)h << 16);
}
__device__ __forceinline__ float tanh_fast(float y) {
  y = fminf(15.f, fmaxf(-15.f, y));
  float t = __expf(2.f * y);
  return (t - 1.f) / (t + 1.f);
}
struct HiLo { short hi, lo; };
__device__ __forceinline__ HiLo split1(float v) {
  HiLo r;
  unsigned short h = f2bf(v);
  r.hi = (short)h;
  r.lo = (short)f2bf(v - bf2f(h));
  return r;
}
__device__ __forceinline__ void ldw8s(const float* p, s16x8& hi, s16x8& lo) {
  float4v a = *(const float4v*)p;
  float4v b = *(const float4v*)(p + 4);
#pragma unroll
  for (int i = 0; i < 4; ++i) {
    HiLo x = split1(a[i]); hi[i] = x.hi; lo[i] = x.lo;
    HiLo y = split1(b[i]); hi[4 + i] = y.hi; lo[4 + i] = y.lo;
  }
}

// ---- L3-direct (sc0 sc1) data path: no cache-wide maintenance ops anywhere ----
// 32 contiguous floats, bypassing L1+L2 (served at Infinity Cache / mem-side)
__device__ __forceinline__ void ld32_sys(const float* p, float* f) {
  float4v a0, a1, a2, a3, a4, a5, a6, a7;
  asm volatile(
      "global_load_dwordx4 %0, %8, off sc0 sc1\n\t"
      "global_load_dwordx4 %1, %8, off offset:16 sc0 sc1\n\t"
      "global_load_dwordx4 %2, %8, off offset:32 sc0 sc1\n\t"
      "global_load_dwordx4 %3, %8, off offset:48 sc0 sc1\n\t"
      "global_load_dwordx4 %4, %8, off offset:64 sc0 sc1\n\t"
      "global_load_dwordx4 %5, %8, off offset:80 sc0 sc1\n\t"
      "global_load_dwordx4 %6, %8, off offset:96 sc0 sc1\n\t"
      "global_load_dwordx4 %7, %8, off offset:112 sc0 sc1\n\t"
      "s_waitcnt vmcnt(0)"
      : "=&v"(a0), "=&v"(a1), "=&v"(a2), "=&v"(a3),
        "=&v"(a4), "=&v"(a5), "=&v"(a6), "=&v"(a7)
      : "v"(p)
      : "memory");
  *(float4v*)&f[0] = a0;  *(float4v*)&f[4] = a1;
  *(float4v*)&f[8] = a2;  *(float4v*)&f[12] = a3;
  *(float4v*)&f[16] = a4; *(float4v*)&f[20] = a5;
  *(float4v*)&f[24] = a6; *(float4v*)&f[28] = a7;
}
__device__ __forceinline__ void st1_sys(float* p, float v) {
  asm volatile("global_store_dword %0, %1, off sc0 sc1" :: "v"(p), "v"(v) : "memory");
}
// drain own wave's vmem (data at L3) before flag RMW; no wbl2
__device__ __forceinline__ void relfence() { asm volatile("s_waitcnt vmcnt(0)" ::: "memory"); }
__device__ __forceinline__ void addrel(int* p) {
  __hip_atomic_fetch_add(p, 1, __ATOMIC_RELAXED, __HIP_MEMORY_SCOPE_SYSTEM);
}
// relaxed system poll with exponential backoff (cap ~0.2us); L3-direct, always fresh
__device__ __forceinline__ void spinR(int* p, int target) {
  int n = 0;
  while (__hip_atomic_load(p, __ATOMIC_RELAXED, __HIP_MEMORY_SCOPE_SYSTEM) < target) {
    if (n < 4) __builtin_amdgcn_s_sleep(1);
    else if (n < 16) __builtin_amdgcn_s_sleep(4);
    else __builtin_amdgcn_s_sleep(8);
    if (++n > 2000000) return;  // safety: wrong data instead of hang
  }
}

// swizzled LDS ushort index: 16B chunk XOR'd with row low bits
__device__ __forceinline__ int chix(int r, int c) {
  return r * 1032 + ((((c >> 3) ^ (r & 3))) << 3) + (c & 7);
}

// ---- staging (512 threads; r=tid>>5 in 0..15, k=tid&31 owns cols 32k..32k+31) ----
__device__ __forceinline__ void stageF32(const float* src, ushort_t* dh, ushort_t* dl, int tid) {
  int r = tid >> 5, k = tid & 31, c0 = k * 32;
  const float* p = src + (size_t)r * H_ + c0;
  float f[32];
#pragma unroll
  for (int q = 0; q < 8; ++q) {
    float4v v = *(const float4v*)(p + q * 4);
#pragma unroll
    for (int i = 0; i < 4; ++i) f[q * 4 + i] = v[i];
  }
#pragma unroll
  for (int i = 0; i < 4; ++i) {
    int q = (i + k) & 3;
    s16x8 hi, lo;
#pragma unroll
    for (int j = 0; j < 8; ++j) { HiLo x = split1(f[q * 8 + j]); hi[j] = x.hi; lo[j] = x.lo; }
    int ix = chix(r, c0 + q * 8);
    *(s16x8*)&dh[ix] = hi; *(s16x8*)&dl[ix] = lo;
  }
}
__device__ __forceinline__ void stageX(const float* src, ushort_t* dh, ushort_t* dl, int tid) {
  int r = tid >> 5, k = tid & 31, c0 = k * 16;
  const float* p = src + (size_t)r * IN_ + c0;
  float f[16];
#pragma unroll
  for (int q = 0; q < 4; ++q) {
    float4v v = *(const float4v*)(p + q * 4);
#pragma unroll
    for (int i = 0; i < 4; ++i) f[q * 4 + i] = v[i];
  }
#pragma unroll
  for (int i = 0; i < 2; ++i) {
    int q = (i + k) & 1;
    s16x8 hi, lo;
#pragma unroll
    for (int j = 0; j < 8; ++j) { HiLo x = split1(f[q * 8 + j]); hi[j] = x.hi; lo[j] = x.lo; }
    int ix = chix(r, c0 + q * 8);
    *(s16x8*)&dh[ix] = hi; *(s16x8*)&dl[ix] = lo;
  }
}
// fp32 pre rows (L3-direct loads) -> LN+tanh -> split LDS; thread k==cgsel writes fp32 to gA/gB
__device__ __forceinline__ void stageLT(const float* src, ushort_t* dh, ushort_t* dl,
                                        const float* lnw, const float* lnb, int tid,
                                        int cgsel, float* gA, float* gB) {
  int r = tid >> 5, k = tid & 31, c0 = k * 32;
  const float* p = src + (size_t)r * H_ + c0;
  float f[32];
  ld32_sys(p, f);
  float s = 0.f, ss = 0.f;
#pragma unroll
  for (int i = 0; i < 32; ++i) { s += f[i]; ss += f[i] * f[i]; }
#pragma unroll
  for (int m = 1; m <= 16; m <<= 1) { s += __shfl_xor(s, m, 64); ss += __shfl_xor(ss, m, 64); }
  float mu = s * (1.f / H_);
  float var = ss * (1.f / H_) - mu * mu;
  float rs = rsqrtf(var + LNEPS);
  // permuted LN-param layout: logical 32k+c stored at 32k+((c+k)&31) -> conflict-free
#pragma unroll
  for (int c = 0; c < 32; ++c) {
    float w = lnw[c0 + ((c + k) & 31)];
    float b = lnb[c0 + ((c + k) & 31)];
    float y = (f[c] - mu) * rs * w + b;
    f[c] = tanh_fast(y);
  }
  if (cgsel >= 0 && k == cgsel) {
    float* pa = gA + (size_t)r * H_ + c0;
#pragma unroll
    for (int q = 0; q < 8; ++q) *(float4v*)(pa + q * 4) = *(const float4v*)&f[q * 4];
    if (gB) {
      float* pb = gB + (size_t)r * H_ + c0;
#pragma unroll
      for (int q = 0; q < 8; ++q) *(float4v*)(pb + q * 4) = *(const float4v*)&f[q * 4];
    }
  }
#pragma unroll
  for (int i = 0; i < 4; ++i) {
    int q = (i + k) & 3;
    s16x8 hi, lo;
#pragma unroll
    for (int j = 0; j < 8; ++j) { HiLo x = split1(f[q * 8 + j]); hi[j] = x.hi; lo[j] = x.lo; }
    int ix = chix(r, c0 + q * 8);
    *(s16x8*)&dh[ix] = hi; *(s16x8*)&dl[ix] = lo;
  }
}

#define MFMA(a, b, c) __builtin_amdgcn_mfma_f32_16x16x32_bf16(a, b, c, 0, 0, 0)
#define AF(buf, idx) (*(const s16x8*)&buf[chix(lane & 15, (idx) + kb8)])

__global__ __launch_bounds__(512, 1) void rnn_persist(
    const float* __restrict__ input, const float* __restrict__ hidden,
    const float* __restrict__ W_ih0, const float* __restrict__ W_hh0,
    const float* __restrict__ b_ih0, const float* __restrict__ b_hh0,
    const float* __restrict__ ln_w0, const float* __restrict__ ln_b0,
    const float* __restrict__ W_ih1, const float* __restrict__ W_hh1,
    const float* __restrict__ b_ih1, const float* __restrict__ b_hh1,
    const float* __restrict__ ln_w1, const float* __restrict__ ln_b1,
    float* gout, float* pre0, float* pre1, int* flag0, int* flag1) {
  __shared__ ushort_t sAh[16 * 1032];
  __shared__ ushort_t sAl[16 * 1032];
  __shared__ float slnw0[1024], slnb0[1024];
  __shared__ float slnw1[1024], slnb1[1024];
  __shared__ float sacc[2][3][16][16];

  const int tid = threadIdx.x;
  const int lane = tid & 63;
  const int w = tid >> 6;
  const int colt = w & 1, kh = w >> 1;
  const int blk = blockIdx.x;
  const int layer = blk >> 7;
  const int id = blk & 127;
  const int rg = id >> 5, cg = id & 31;
  const int rowbase = rg * RB;
  const int cgl = cg * 32 + colt * 16 + (lane & 15);
  const int kb8 = (lane >> 4) * 8;
  const int l15 = lane & 15;

  for (int i = tid; i < H_; i += 512) {
    int pi = (i & ~31) | ((i + (i >> 5)) & 31);
    slnw0[pi] = ln_w0[i]; slnb0[pi] = ln_b0[i];
    slnw1[pi] = ln_w1[i]; slnb1[pi] = ln_b1[i];
  }

  float bias = 0.f;

  if (layer == 0) {
    s16x8 WhiX[4], WloX[4], WhiH[8], WloH[8];
#pragma unroll
    for (int s = 0; s < 4; ++s)
      ldw8s(W_ih0 + (size_t)cgl * IN_ + kh * 128 + s * 32 + kb8, WhiX[s], WloX[s]);
#pragma unroll
    for (int s = 0; s < 8; ++s)
      ldw8s(W_hh0 + (size_t)cgl * H_ + kh * 256 + s * 32 + kb8, WhiH[s], WloH[s]);
    if (kh == 0) bias = b_ih0[cgl] + b_hh0[cgl];
    __syncthreads();

    for (int t = 0; t < T_; ++t) {
      stageX(input + ((size_t)t * B_ + rowbase) * IN_, sAh, sAl, tid);
      __syncthreads();
      f32x4 aP = (kh == 0) ? (f32x4){bias, bias, bias, bias} : (f32x4){0.f, 0.f, 0.f, 0.f};
      f32x4 aQ = {0.f, 0.f, 0.f, 0.f}, aR = {0.f, 0.f, 0.f, 0.f};
#pragma unroll
      for (int s = 0; s < 4; ++s) {
        s16x8 ah = AF(sAh, kh * 128 + s * 32), al = AF(sAl, kh * 128 + s * 32);
        aP = MFMA(ah, WhiX[s], aP); aQ = MFMA(ah, WloX[s], aQ); aR = MFMA(al, WhiX[s], aR);
      }
      if (tid == 0 && t > 0) spinR(&flag0[(t - 1) * 4 + rg], NCG);
      if (tid == 64 && t >= RING) spinR(&flag1[(t - RING) * 4 + rg], NCG);
      __syncthreads();
      if (t == 0) stageF32(hidden + (size_t)rowbase * H_, sAh, sAl, tid);
      else stageLT(pre0 + ((size_t)((t - 1) & 7) * B_ + rowbase) * H_, sAh, sAl,
                   slnw0, slnb0, tid, -1, nullptr, nullptr);
      __syncthreads();
#pragma unroll
      for (int s = 0; s < 8; ++s) {
        s16x8 ah = AF(sAh, kh * 256 + s * 32), al = AF(sAl, kh * 256 + s * 32);
        aP = MFMA(ah, WhiH[s], aP); aQ = MFMA(ah, WloH[s], aQ); aR = MFMA(al, WhiH[s], aR);
      }
      f32x4 sum = aP + aQ + aR;
      if (kh > 0) {
#pragma unroll
        for (int j = 0; j < 4; ++j) sacc[colt][kh - 1][(lane >> 4) * 4 + j][l15] = sum[j];
      }
      __syncthreads();
      if (kh == 0) {
        float* dst = pre0 + ((size_t)(t & 7) * B_ + rowbase) * H_;
#pragma unroll
        for (int j = 0; j < 4; ++j) {
          int row = (lane >> 4) * 4 + j;
          float v = sum[j] + sacc[colt][0][row][l15] + sacc[colt][1][row][l15] +
                    sacc[colt][2][row][l15];
          st1_sys(&dst[(size_t)row * H_ + cgl], v);
        }
        relfence();  // own wave's sc1 stores are at L3
      }
      __syncthreads();
      if (tid == 0) addrel(&flag0[t * 4 + rg]);
    }
    // epilogue: h_fin[0] slice
    if (tid == 0) spinR(&flag0[(T_ - 1) * 4 + rg], NCG);
    __syncthreads();
    stageLT(pre0 + ((size_t)((T_ - 1) & 7) * B_ + rowbase) * H_, sAh, sAl, slnw0, slnb0,
            tid, cg, gout + (size_t)T_ * B_ * H_ + (size_t)rowbase * H_, nullptr);
  } else {
    s16x8 WhiA[8], WloA[8], WhiB[8], WloB[8];
#pragma unroll
    for (int s = 0; s < 8; ++s)
      ldw8s(W_hh1 + (size_t)cgl * H_ + kh * 256 + s * 32 + kb8, WhiA[s], WloA[s]);
#pragma unroll
    for (int s = 0; s < 8; ++s)
      ldw8s(W_ih1 + (size_t)cgl * H_ + kh * 256 + s * 32 + kb8, WhiB[s], WloB[s]);
    if (kh == 0) bias = b_ih1[cgl] + b_hh1[cgl];
    __syncthreads();

    for (int t = 0; t < T_; ++t) {
      if (tid == 0) spinR(&flag0[t * 4 + rg], NCG);
      if (tid == 64 && t > 0) spinR(&flag1[(t - 1) * 4 + rg], NCG);
      __syncthreads();
      // h0[t] phase (flag0[t] pre-satisfied in steady state: L0 runs ahead)
      stageLT(pre0 + ((size_t)(t & 7) * B_ + rowbase) * H_, sAh, sAl,
              slnw0, slnb0, tid, -1, nullptr, nullptr);
      __syncthreads();
      f32x4 aP = (kh == 0) ? (f32x4){bias, bias, bias, bias} : (f32x4){0.f, 0.f, 0.f, 0.f};
      f32x4 aQ = {0.f, 0.f, 0.f, 0.f}, aR = {0.f, 0.f, 0.f, 0.f};
#pragma unroll
      for (int s = 0; s < 8; ++s) {
        s16x8 ah = AF(sAh, kh * 256 + s * 32), al = AF(sAl, kh * 256 + s * 32);
        aP = MFMA(ah, WhiB[s], aP); aQ = MFMA(ah, WloB[s], aQ); aR = MFMA(al, WhiB[s], aR);
      }
      __syncthreads();
      // h1[t-1] phase: consumer-side LN1+tanh; writes gout[t-1] slice
      if (t == 0) stageF32(hidden + (size_t)B_ * H_ + (size_t)rowbase * H_, sAh, sAl, tid);
      else stageLT(pre1 + ((size_t)((t - 1) & 7) * B_ + rowbase) * H_, sAh, sAl,
                   slnw1, slnb1, tid, cg,
                   gout + ((size_t)(t - 1) * B_ + rowbase) * H_, nullptr);
      __syncthreads();
#pragma unroll
      for (int s = 0; s < 8; ++s) {
        s16x8 ah = AF(sAh, kh * 256 + s * 32), al = AF(sAl, kh * 256 + s * 32);
        aP = MFMA(ah, WhiA[s], aP); aQ = MFMA(ah, WloA[s], aQ); aR = MFMA(al, WhiA[s], aR);
      }
      f32x4 sum = aP + aQ + aR;
      if (kh > 0) {
#pragma unroll
        for (int j = 0; j < 4; ++j) sacc[colt][kh - 1][(lane >> 4) * 4 + j][l15] = sum[j];
      }
      __syncthreads();
      if (kh == 0) {
        float* dst = pre1 + ((size_t)(t & 7) * B_ + rowbase) * H_;
#pragma unroll
        for (int j = 0; j < 4; ++j) {
          int row = (lane >> 4) * 4 + j;
          float v = sum[j] + sacc[colt][0][row][l15] + sacc[colt][1][row][l15] +
                    sacc[colt][2][row][l15];
          st1_sys(&dst[(size_t)row * H_ + cgl], v);
        }
        relfence();
      }
      __syncthreads();
      if (tid == 0) addrel(&flag1[t * 4 + rg]);
    }
    // epilogue: gout[T-1] + h_fin[1] slices
    if (tid == 0) spinR(&flag1[(T_ - 1) * 4 + rg], NCG);
    __syncthreads();
    stageLT(pre1 + ((size_t)((T_ - 1) & 7) * B_ + rowbase) * H_, sAh, sAl, slnw1, slnb1,
            tid, cg, gout + ((size_t)(T_ - 1) * B_ + rowbase) * H_,
            gout + (size_t)T_ * B_ * H_ + (size_t)B_ * H_ + (size_t)rowbase * H_);
  }
}

extern "C" void kernel_launch(void* const* d_in, const int* in_sizes, int n_in,
                              void* d_out, int out_size, void* d_ws, size_t ws_size,
                              hipStream_t stream) {
  const float* input = (const float*)d_in[0];
  const float* hidden = (const float*)d_in[1];
  const float* W_ih0 = (const float*)d_in[2];
  const float* W_hh0 = (const float*)d_in[3];
  const float* b_ih0 = (const float*)d_in[4];
  const float* b_hh0 = (const float*)d_in[5];
  const float* ln_w0 = (const float*)d_in[6];
  const float* ln_b0 = (const float*)d_in[7];
  const float* W_ih1 = (const float*)d_in[8];
  const float* W_hh1 = (const float*)d_in[9];
  const float* b_ih1 = (const float*)d_in[10];
  const float* b_hh1 = (const float*)d_in[11];
  const float* ln_w1 = (const float*)d_in[12];
  const float* ln_b1 = (const float*)d_in[13];
  float* gout = (float*)d_out;

  char* ws = (char*)d_ws;
  float* pre0 = (float*)ws;                     // 2 MB ring
  float* pre1 = (float*)(ws + (2u << 20));      // 2 MB ring
  char* ctrl = ws + (4u << 20);
  int* flag0 = (int*)ctrl;                      // 8 KB
  int* flag1 = (int*)(ctrl + 8192);             // 8 KB

  (void)hipMemsetAsync(ctrl, 0, 16384, stream);
  hipLaunchKernelGGL(rnn_persist, dim3(256), dim3(512), 0, stream,
                     input, hidden, W_ih0, W_hh0, b_ih0, b_hh0, ln_w0, ln_b0,
                     W_ih1, W_hh1, b_ih1, b_hh1, ln_w1, ln_b1,
                     gout, pre0, pre1, flag0, flag1);
}

// Round 6
// 20059.172 us; speedup vs baseline: 2.0167x; 1.7016x over previous
//
#include <hip/hip_runtime.h>
#include <stdint.h>

#define T_ 512
#define B_ 64
#define IN_ 512
#define H_ 1024
#define RB 16
#define NCG 32
#define RING 8
#define LNEPS 1e-5f
#define FIDX(t, rg) ((((t) * 4 + (rg)) << 4))

typedef __attribute__((ext_vector_type(8))) short s16x8;
typedef __attribute__((ext_vector_type(4))) float f32x4;
typedef __attribute__((ext_vector_type(4))) float float4v;
typedef unsigned short ushort_t;

__device__ __forceinline__ unsigned short f2bf(float f) {
  unsigned u = __builtin_bit_cast(unsigned, f);
  return (unsigned short)((u + 0x7FFFu + ((u >> 16) & 1u)) >> 16);
}
__device__ __forceinline__ float bf2f(unsigned short h) {
  return __builtin_bit_cast(float, (unsigned)h << 16);
}
__device__ __forceinline__ float tanh_fast(float y) {
  y = fminf(15.f, fmaxf(-15.f, y));
  float t = __expf(2.f * y);
  return (t - 1.f) / (t + 1.f);
}
struct HiLo { short hi, lo; };
__device__ __forceinline__ HiLo split1(float v) {
  HiLo r;
  unsigned short h = f2bf(v);
  r.hi = (short)h;
  r.lo = (short)f2bf(v - bf2f(h));
  return r;
}
__device__ __forceinline__ void ldw8s(const float* p, s16x8& hi, s16x8& lo) {
  float4v a = *(const float4v*)p;
  float4v b = *(const float4v*)(p + 4);
#pragma unroll
  for (int i = 0; i < 4; ++i) {
    HiLo x = split1(a[i]); hi[i] = x.hi; lo[i] = x.lo;
    HiLo y = split1(b[i]); hi[4 + i] = y.hi; lo[4 + i] = y.lo;
  }
}

// ---- L3-direct (sc0 sc1) data path: no cache-wide maintenance ops anywhere ----
__device__ __forceinline__ void ld32_sys(const float* p, float* f) {
  float4v a0, a1, a2, a3, a4, a5, a6, a7;
  asm volatile(
      "global_load_dwordx4 %0, %8, off sc0 sc1\n\t"
      "global_load_dwordx4 %1, %8, off offset:16 sc0 sc1\n\t"
      "global_load_dwordx4 %2, %8, off offset:32 sc0 sc1\n\t"
      "global_load_dwordx4 %3, %8, off offset:48 sc0 sc1\n\t"
      "global_load_dwordx4 %4, %8, off offset:64 sc0 sc1\n\t"
      "global_load_dwordx4 %5, %8, off offset:80 sc0 sc1\n\t"
      "global_load_dwordx4 %6, %8, off offset:96 sc0 sc1\n\t"
      "global_load_dwordx4 %7, %8, off offset:112 sc0 sc1\n\t"
      "s_waitcnt vmcnt(0)"
      : "=&v"(a0), "=&v"(a1), "=&v"(a2), "=&v"(a3),
        "=&v"(a4), "=&v"(a5), "=&v"(a6), "=&v"(a7)
      : "v"(p)
      : "memory");
  *(float4v*)&f[0] = a0;  *(float4v*)&f[4] = a1;
  *(float4v*)&f[8] = a2;  *(float4v*)&f[12] = a3;
  *(float4v*)&f[16] = a4; *(float4v*)&f[20] = a5;
  *(float4v*)&f[24] = a6; *(float4v*)&f[28] = a7;
}
__device__ __forceinline__ void st1_sys(float* p, float v) {
  asm volatile("global_store_dword %0, %1, off sc0 sc1" :: "v"(p), "v"(v) : "memory");
}
__device__ __forceinline__ void relfence() { asm volatile("s_waitcnt vmcnt(0)" ::: "memory"); }
__device__ __forceinline__ void addrel(int* p) {
  __hip_atomic_fetch_add(p, 1, __ATOMIC_RELAXED, __HIP_MEMORY_SCOPE_SYSTEM);
}
__device__ __forceinline__ void spinR(int* p, int target) {
  int n = 0;
  while (__hip_atomic_load(p, __ATOMIC_RELAXED, __HIP_MEMORY_SCOPE_SYSTEM) < target) {
    if (n < 4) __builtin_amdgcn_s_sleep(1);
    else if (n < 16) __builtin_amdgcn_s_sleep(4);
    else __builtin_amdgcn_s_sleep(8);
    if (++n > 2000000) return;  // safety: wrong data instead of hang
  }
}

// LDS swizzle: chunk = 16B unit; fold row AND column-owner bits into bank bits.
// phys low2(chunk) = (ch ^ r ^ (ch>>2)) & 3  -> stage writes ~2-way, AF reads ~2-way.
__device__ __forceinline__ int chix(int r, int c) {
  int ch = c >> 3;
  int low = (ch ^ r ^ (ch >> 2)) & 3;
  return r * 1032 + ((((ch >> 2) << 2) | low) << 3) + (c & 7);
}

// ---- staging (512 threads; r=tid>>5 in 0..15, k=tid&31 owns cols 32k..32k+31) ----
__device__ __forceinline__ void stageF32(const float* src, ushort_t* dh, ushort_t* dl, int tid) {
  int r = tid >> 5, k = tid & 31, c0 = k * 32;
  const float* p = src + (size_t)r * H_ + c0;
#pragma unroll
  for (int q = 0; q < 4; ++q) {
    float4v a = *(const float4v*)(p + q * 8);
    float4v b = *(const float4v*)(p + q * 8 + 4);
    s16x8 hi, lo;
#pragma unroll
    for (int i = 0; i < 4; ++i) {
      HiLo x = split1(a[i]); hi[i] = x.hi; lo[i] = x.lo;
      HiLo y = split1(b[i]); hi[4 + i] = y.hi; lo[4 + i] = y.lo;
    }
    int ix = chix(r, c0 + q * 8);
    *(s16x8*)&dh[ix] = hi; *(s16x8*)&dl[ix] = lo;
  }
}
__device__ __forceinline__ void stageX(const float* src, ushort_t* dh, ushort_t* dl, int tid) {
  int r = tid >> 5, k = tid & 31, c0 = k * 16;
  const float* p = src + (size_t)r * IN_ + c0;
#pragma unroll
  for (int q = 0; q < 2; ++q) {
    float4v a = *(const float4v*)(p + q * 8);
    float4v b = *(const float4v*)(p + q * 8 + 4);
    s16x8 hi, lo;
#pragma unroll
    for (int i = 0; i < 4; ++i) {
      HiLo x = split1(a[i]); hi[i] = x.hi; lo[i] = x.lo;
      HiLo y = split1(b[i]); hi[4 + i] = y.hi; lo[4 + i] = y.lo;
    }
    int ix = chix(r, c0 + q * 8);
    *(s16x8*)&dh[ix] = hi; *(s16x8*)&dl[ix] = lo;
  }
}
// fp32 pre rows (L3-direct) -> LN+tanh -> split LDS; thread k==cgsel writes fp32 to gA/gB.
// ALL private-array indices are compile-time constants (no scratch).
__device__ __forceinline__ void stageLT(const float* src, ushort_t* dh, ushort_t* dl,
                                        const float* lnw, const float* lnb, int tid,
                                        int cgsel, float* gA, float* gB) {
  int r = tid >> 5, k = tid & 31, c0 = k * 32;
  const float* p = src + (size_t)r * H_ + c0;
  float f[32];
  ld32_sys(p, f);
  float s = 0.f, ss = 0.f;
#pragma unroll
  for (int i = 0; i < 32; ++i) { s += f[i]; ss += f[i] * f[i]; }
#pragma unroll
  for (int m = 1; m <= 16; m <<= 1) { s += __shfl_xor(s, m, 64); ss += __shfl_xor(ss, m, 64); }
  float mu = s * (1.f / H_);
  float var = ss * (1.f / H_) - mu * mu;
  float rs = rsqrtf(var + LNEPS);
  // permuted LN-param layout: logical 32k+c stored at 32k+((c+k)&31) -> conflict-free LDS read
#pragma unroll
  for (int c = 0; c < 32; ++c) {
    float w = lnw[c0 + ((c + k) & 31)];
    float b = lnb[c0 + ((c + k) & 31)];
    float y = (f[c] - mu) * rs * w + b;
    f[c] = tanh_fast(y);
  }
  if (cgsel >= 0 && k == cgsel) {
    float* pa = gA + (size_t)r * H_ + c0;
#pragma unroll
    for (int q = 0; q < 8; ++q) *(float4v*)(pa + q * 4) = *(const float4v*)&f[q * 4];
    if (gB) {
      float* pb = gB + (size_t)r * H_ + c0;
#pragma unroll
      for (int q = 0; q < 8; ++q) *(float4v*)(pb + q * 4) = *(const float4v*)&f[q * 4];
    }
  }
#pragma unroll
  for (int q = 0; q < 4; ++q) {
    s16x8 hi, lo;
#pragma unroll
    for (int j = 0; j < 8; ++j) { HiLo x = split1(f[q * 8 + j]); hi[j] = x.hi; lo[j] = x.lo; }
    int ix = chix(r, c0 + q * 8);
    *(s16x8*)&dh[ix] = hi; *(s16x8*)&dl[ix] = lo;
  }
}

#define MFMA(a, b, c) __builtin_amdgcn_mfma_f32_16x16x32_bf16(a, b, c, 0, 0, 0)
#define AF(buf, idx) (*(const s16x8*)&buf[chix(lane & 15, (idx) + kb8)])

__global__ __launch_bounds__(512, 1) void rnn_persist(
    const float* __restrict__ input, const float* __restrict__ hidden,
    const float* __restrict__ W_ih0, const float* __restrict__ W_hh0,
    const float* __restrict__ b_ih0, const float* __restrict__ b_hh0,
    const float* __restrict__ ln_w0, const float* __restrict__ ln_b0,
    const float* __restrict__ W_ih1, const float* __restrict__ W_hh1,
    const float* __restrict__ b_ih1, const float* __restrict__ b_hh1,
    const float* __restrict__ ln_w1, const float* __restrict__ ln_b1,
    float* gout, float* pre0, float* pre1, int* flag0, int* flag1) {
  __shared__ ushort_t sAh[16 * 1032];
  __shared__ ushort_t sAl[16 * 1032];
  __shared__ float slnw0[1024], slnb0[1024];
  __shared__ float slnw1[1024], slnb1[1024];
  __shared__ float sacc[2][3][16][16];

  const int tid = threadIdx.x;
  const int lane = tid & 63;
  const int w = tid >> 6;
  const int colt = w & 1, kh = w >> 1;
  const int blk = blockIdx.x;
  const int layer = blk >> 7;
  const int id = blk & 127;
  const int rg = id >> 5, cg = id & 31;
  const int rowbase = rg * RB;
  const int cgl = cg * 32 + colt * 16 + (lane & 15);
  const int kb8 = (lane >> 4) * 8;
  const int l15 = lane & 15;

  for (int i = tid; i < H_; i += 512) {
    int pi = (i & ~31) | ((i + (i >> 5)) & 31);
    slnw0[pi] = ln_w0[i]; slnb0[pi] = ln_b0[i];
    slnw1[pi] = ln_w1[i]; slnb1[pi] = ln_b1[i];
  }

  float bias = 0.f;

  if (layer == 0) {
    s16x8 WhiX[4], WloX[4], WhiH[8], WloH[8];
#pragma unroll
    for (int s = 0; s < 4; ++s)
      ldw8s(W_ih0 + (size_t)cgl * IN_ + kh * 128 + s * 32 + kb8, WhiX[s], WloX[s]);
#pragma unroll
    for (int s = 0; s < 8; ++s)
      ldw8s(W_hh0 + (size_t)cgl * H_ + kh * 256 + s * 32 + kb8, WhiH[s], WloH[s]);
    if (kh == 0) bias = b_ih0[cgl] + b_hh0[cgl];
    __syncthreads();

    for (int t = 0; t < T_; ++t) {
      stageX(input + ((size_t)t * B_ + rowbase) * IN_, sAh, sAl, tid);
      __syncthreads();
      f32x4 aP = (kh == 0) ? (f32x4){bias, bias, bias, bias} : (f32x4){0.f, 0.f, 0.f, 0.f};
      f32x4 aQ = {0.f, 0.f, 0.f, 0.f}, aR = {0.f, 0.f, 0.f, 0.f};
#pragma unroll
      for (int s = 0; s < 4; ++s) {
        s16x8 ah = AF(sAh, kh * 128 + s * 32), al = AF(sAl, kh * 128 + s * 32);
        aP = MFMA(ah, WhiX[s], aP); aQ = MFMA(ah, WloX[s], aQ); aR = MFMA(al, WhiX[s], aR);
      }
      if (tid == 0 && t > 0) spinR(&flag0[FIDX(t - 1, rg)], NCG);
      if (tid == 64 && t >= RING) spinR(&flag1[FIDX(t - RING, rg)], NCG);
      __syncthreads();
      if (t == 0) stageF32(hidden + (size_t)rowbase * H_, sAh, sAl, tid);
      else stageLT(pre0 + ((size_t)((t - 1) & 7) * B_ + rowbase) * H_, sAh, sAl,
                   slnw0, slnb0, tid, -1, nullptr, nullptr);
      __syncthreads();
#pragma unroll
      for (int s = 0; s < 8; ++s) {
        s16x8 ah = AF(sAh, kh * 256 + s * 32), al = AF(sAl, kh * 256 + s * 32);
        aP = MFMA(ah, WhiH[s], aP); aQ = MFMA(ah, WloH[s], aQ); aR = MFMA(al, WhiH[s], aR);
      }
      f32x4 sum = aP + aQ + aR;
      if (kh > 0) {
#pragma unroll
        for (int j = 0; j < 4; ++j) sacc[colt][kh - 1][(lane >> 4) * 4 + j][l15] = sum[j];
      }
      __syncthreads();
      if (kh == 0) {
        float* dst = pre0 + ((size_t)(t & 7) * B_ + rowbase) * H_;
#pragma unroll
        for (int j = 0; j < 4; ++j) {
          int row = (lane >> 4) * 4 + j;
          float v = sum[j] + sacc[colt][0][row][l15] + sacc[colt][1][row][l15] +
                    sacc[colt][2][row][l15];
          st1_sys(&dst[(size_t)row * H_ + cgl], v);
        }
        relfence();
      }
      __syncthreads();
      if (tid == 0) addrel(&flag0[FIDX(t, rg)]);
    }
    // epilogue: h_fin[0] slice
    if (tid == 0) spinR(&flag0[FIDX(T_ - 1, rg)], NCG);
    __syncthreads();
    stageLT(pre0 + ((size_t)((T_ - 1) & 7) * B_ + rowbase) * H_, sAh, sAl, slnw0, slnb0,
            tid, cg, gout + (size_t)T_ * B_ * H_ + (size_t)rowbase * H_, nullptr);
  } else {
    s16x8 WhiA[8], WloA[8], WhiB[8], WloB[8];
#pragma unroll
    for (int s = 0; s < 8; ++s)
      ldw8s(W_hh1 + (size_t)cgl * H_ + kh * 256 + s * 32 + kb8, WhiA[s], WloA[s]);
#pragma unroll
    for (int s = 0; s < 8; ++s)
      ldw8s(W_ih1 + (size_t)cgl * H_ + kh * 256 + s * 32 + kb8, WhiB[s], WloB[s]);
    if (kh == 0) bias = b_ih1[cgl] + b_hh1[cgl];
    __syncthreads();

    for (int t = 0; t < T_; ++t) {
      if (tid == 0) spinR(&flag0[FIDX(t, rg)], NCG);
      if (tid == 64 && t > 0) spinR(&flag1[FIDX(t - 1, rg)], NCG);
      __syncthreads();
      // h0[t] phase (flag0[t] pre-satisfied in steady state: L0 runs ahead)
      stageLT(pre0 + ((size_t)(t & 7) * B_ + rowbase) * H_, sAh, sAl,
              slnw0, slnb0, tid, -1, nullptr, nullptr);
      __syncthreads();
      f32x4 aP = (kh == 0) ? (f32x4){bias, bias, bias, bias} : (f32x4){0.f, 0.f, 0.f, 0.f};
      f32x4 aQ = {0.f, 0.f, 0.f, 0.f}, aR = {0.f, 0.f, 0.f, 0.f};
#pragma unroll
      for (int s = 0; s < 8; ++s) {
        s16x8 ah = AF(sAh, kh * 256 + s * 32), al = AF(sAl, kh * 256 + s * 32);
        aP = MFMA(ah, WhiB[s], aP); aQ = MFMA(ah, WloB[s], aQ); aR = MFMA(al, WhiB[s], aR);
      }
      __syncthreads();
      // h1[t-1] phase: consumer-side LN1+tanh; writes gout[t-1] slice
      if (t == 0) stageF32(hidden + (size_t)B_ * H_ + (size_t)rowbase * H_, sAh, sAl, tid);
      else stageLT(pre1 + ((size_t)((t - 1) & 7) * B_ + rowbase) * H_, sAh, sAl,
                   slnw1, slnb1, tid, cg,
                   gout + ((size_t)(t - 1) * B_ + rowbase) * H_, nullptr);
      __syncthreads();
#pragma unroll
      for (int s = 0; s < 8; ++s) {
        s16x8 ah = AF(sAh, kh * 256 + s * 32), al = AF(sAl, kh * 256 + s * 32);
        aP = MFMA(ah, WhiA[s], aP); aQ = MFMA(ah, WloA[s], aQ); aR = MFMA(al, WhiA[s], aR);
      }
      f32x4 sum = aP + aQ + aR;
      if (kh > 0) {
#pragma unroll
        for (int j = 0; j < 4; ++j) sacc[colt][kh - 1][(lane >> 4) * 4 + j][l15] = sum[j];
      }
      __syncthreads();
      if (kh == 0) {
        float* dst = pre1 + ((size_t)(t & 7) * B_ + rowbase) * H_;
#pragma unroll
        for (int j = 0; j < 4; ++j) {
          int row = (lane >> 4) * 4 + j;
          float v = sum[j] + sacc[colt][0][row][l15] + sacc[colt][1][row][l15] +
                    sacc[colt][2][row][l15];
          st1_sys(&dst[(size_t)row * H_ + cgl], v);
        }
        relfence();
      }
      __syncthreads();
      if (tid == 0) addrel(&flag1[FIDX(t, rg)]);
    }
    // epilogue: gout[T-1] + h_fin[1] slices
    if (tid == 0) spinR(&flag1[FIDX(T_ - 1, rg)], NCG);
    __syncthreads();
    stageLT(pre1 + ((size_t)((T_ - 1) & 7) * B_ + rowbase) * H_, sAh, sAl, slnw1, slnb1,
            tid, cg, gout + ((size_t)(T_ - 1) * B_ + rowbase) * H_,
            gout + (size_t)T_ * B_ * H_ + (size_t)B_ * H_ + (size_t)rowbase * H_);
  }
}

extern "C" void kernel_launch(void* const* d_in, const int* in_sizes, int n_in,
                              void* d_out, int out_size, void* d_ws, size_t ws_size,
                              hipStream_t stream) {
  const float* input = (const float*)d_in[0];
  const float* hidden = (const float*)d_in[1];
  const float* W_ih0 = (const float*)d_in[2];
  const float* W_hh0 = (const float*)d_in[3];
  const float* b_ih0 = (const float*)d_in[4];
  const float* b_hh0 = (const float*)d_in[5];
  const float* ln_w0 = (const float*)d_in[6];
  const float* ln_b0 = (const float*)d_in[7];
  const float* W_ih1 = (const float*)d_in[8];
  const float* W_hh1 = (const float*)d_in[9];
  const float* b_ih1 = (const float*)d_in[10];
  const float* b_hh1 = (const float*)d_in[11];
  const float* ln_w1 = (const float*)d_in[12];
  const float* ln_b1 = (const float*)d_in[13];
  float* gout = (float*)d_out;

  char* ws = (char*)d_ws;
  float* pre0 = (float*)ws;                     // 2 MB ring
  float* pre1 = (float*)(ws + (2u << 20));      // 2 MB ring
  char* ctrl = ws + (4u << 20);
  int* flag0 = (int*)ctrl;                      // 512*4*16*4 = 128 KB (64B-strided flags)
  int* flag1 = (int*)(ctrl + 0x20000);          // 128 KB

  (void)hipMemsetAsync(ctrl, 0, 0x40000, stream);
  hipLaunchKernelGGL(rnn_persist, dim3(256), dim3(512), 0, stream,
                     input, hidden, W_ih0, W_hh0, b_ih0, b_hh0, ln_w0, ln_b0,
                     W_ih1, W_hh1, b_ih1, b_hh1, ln_w1, ln_b1,
                     gout, pre0, pre1, flag0, flag1);
}

// Round 7
// 17878.699 us; speedup vs baseline: 2.2627x; 1.1220x over previous
//
#include <hip/hip_runtime.h>
#include <stdint.h>

#define T_ 512
#define B_ 64
#define IN_ 512
#define H_ 1024
#define RB 16
#define NCG 32
#define RING 8
#define LNEPS 1e-5f
#define FIDX(t, rg) ((((t) * 4 + (rg)) << 4))

typedef __attribute__((ext_vector_type(8))) short s16x8;
typedef __attribute__((ext_vector_type(4))) float f32x4;
typedef __attribute__((ext_vector_type(4))) float float4v;
typedef unsigned short ushort_t;

__device__ __forceinline__ unsigned short f2bf(float f) {
  unsigned u = __builtin_bit_cast(unsigned, f);
  return (unsigned short)((u + 0x7FFFu + ((u >> 16) & 1u)) >> 16);
}
__device__ __forceinline__ float bf2f(unsigned short h) {
  return __builtin_bit_cast(float, (unsigned)h << 16);
}
__device__ __forceinline__ float tanh_fast(float y) {
  y = fminf(15.f, fmaxf(-15.f, y));
  float t = __expf(2.f * y);
  return (t - 1.f) / (t + 1.f);
}
struct HiLo { short hi, lo; };
__device__ __forceinline__ HiLo split1(float v) {
  HiLo r;
  unsigned short h = f2bf(v);
  r.hi = (short)h;
  r.lo = (short)f2bf(v - bf2f(h));
  return r;
}
__device__ __forceinline__ void ldw8s(const float* p, s16x8& hi, s16x8& lo) {
  float4v a = *(const float4v*)p;
  float4v b = *(const float4v*)(p + 4);
#pragma unroll
  for (int i = 0; i < 4; ++i) {
    HiLo x = split1(a[i]); hi[i] = x.hi; lo[i] = x.lo;
    HiLo y = split1(b[i]); hi[4 + i] = y.hi; lo[4 + i] = y.lo;
  }
}

// ---- L3-direct (sc0 sc1) loads: used only in the ring-fallback path ----
__device__ __forceinline__ void ld32_sys(const float* p, float* f) {
  float4v a0, a1, a2, a3, a4, a5, a6, a7;
  asm volatile(
      "global_load_dwordx4 %0, %8, off sc0 sc1\n\t"
      "global_load_dwordx4 %1, %8, off offset:16 sc0 sc1\n\t"
      "global_load_dwordx4 %2, %8, off offset:32 sc0 sc1\n\t"
      "global_load_dwordx4 %3, %8, off offset:48 sc0 sc1\n\t"
      "global_load_dwordx4 %4, %8, off offset:64 sc0 sc1\n\t"
      "global_load_dwordx4 %5, %8, off offset:80 sc0 sc1\n\t"
      "global_load_dwordx4 %6, %8, off offset:96 sc0 sc1\n\t"
      "global_load_dwordx4 %7, %8, off offset:112 sc0 sc1\n\t"
      "s_waitcnt vmcnt(0)"
      : "=&v"(a0), "=&v"(a1), "=&v"(a2), "=&v"(a3),
        "=&v"(a4), "=&v"(a5), "=&v"(a6), "=&v"(a7)
      : "v"(p)
      : "memory");
  *(float4v*)&f[0] = a0;  *(float4v*)&f[4] = a1;
  *(float4v*)&f[8] = a2;  *(float4v*)&f[12] = a3;
  *(float4v*)&f[16] = a4; *(float4v*)&f[20] = a5;
  *(float4v*)&f[24] = a6; *(float4v*)&f[28] = a7;
}
__device__ __forceinline__ void st1_sys(float* p, float v) {
  asm volatile("global_store_dword %0, %1, off sc0 sc1" :: "v"(p), "v"(v) : "memory");
}
__device__ __forceinline__ void relfence() { asm volatile("s_waitcnt vmcnt(0)" ::: "memory"); }
__device__ __forceinline__ void addrel(int* p) {
  __hip_atomic_fetch_add(p, 1, __ATOMIC_RELAXED, __HIP_MEMORY_SCOPE_SYSTEM);
}
__device__ __forceinline__ void spinR(int* p, int target) {
  int n = 0;
  while (__hip_atomic_load(p, __ATOMIC_RELAXED, __HIP_MEMORY_SCOPE_SYSTEM) < target) {
    if (n < 4) __builtin_amdgcn_s_sleep(1);
    else if (n < 16) __builtin_amdgcn_s_sleep(4);
    else __builtin_amdgcn_s_sleep(8);
    if (++n > 2000000) return;  // safety: wrong data instead of hang
  }
}

// LDS swizzle: chunk = 16B unit; fold row and column-owner bits into bank bits.
__device__ __forceinline__ int chix(int r, int c) {
  int ch = c >> 3;
  int low = (ch ^ r ^ (ch >> 2)) & 3;
  return r * 1032 + ((((ch >> 2) << 2) | low) << 3) + (c & 7);
}

// ---- staging (512 threads; r=tid>>5 in 0..15, k=tid&31 owns cols 32k..32k+31) ----
__device__ __forceinline__ void stageF32(const float* src, ushort_t* dh, ushort_t* dl, int tid) {
  int r = tid >> 5, k = tid & 31, c0 = k * 32;
  const float* p = src + (size_t)r * H_ + c0;
#pragma unroll
  for (int q = 0; q < 4; ++q) {
    float4v a = *(const float4v*)(p + q * 8);
    float4v b = *(const float4v*)(p + q * 8 + 4);
    s16x8 hi, lo;
#pragma unroll
    for (int i = 0; i < 4; ++i) {
      HiLo x = split1(a[i]); hi[i] = x.hi; lo[i] = x.lo;
      HiLo y = split1(b[i]); hi[4 + i] = y.hi; lo[4 + i] = y.lo;
    }
    int ix = chix(r, c0 + q * 8);
    *(s16x8*)&dh[ix] = hi; *(s16x8*)&dl[ix] = lo;
  }
}
__device__ __forceinline__ void stageX(const float* src, ushort_t* dh, ushort_t* dl, int tid) {
  int r = tid >> 5, k = tid & 31, c0 = k * 16;
  const float* p = src + (size_t)r * IN_ + c0;
#pragma unroll
  for (int q = 0; q < 2; ++q) {
    float4v a = *(const float4v*)(p + q * 8);
    float4v b = *(const float4v*)(p + q * 8 + 4);
    s16x8 hi, lo;
#pragma unroll
    for (int i = 0; i < 4; ++i) {
      HiLo x = split1(a[i]); hi[i] = x.hi; lo[i] = x.lo;
      HiLo y = split1(b[i]); hi[4 + i] = y.hi; lo[4 + i] = y.lo;
    }
    int ix = chix(r, c0 + q * 8);
    *(s16x8*)&dh[ix] = hi; *(s16x8*)&dl[ix] = lo;
  }
}
// fp32 pre rows -> LN+tanh -> split LDS; thread k==cgsel writes fp32 rows to gA/gB.
// NW=true: plain (cached) loads — valid because addresses are written-once/never-reused.
template <bool NW>
__device__ __forceinline__ void stageLT(const float* src, ushort_t* dh, ushort_t* dl,
                                        const float* lnw, const float* lnb, int tid,
                                        int cgsel, float* gA, float* gB) {
  int r = tid >> 5, k = tid & 31, c0 = k * 32;
  const float* p = src + (size_t)r * H_ + c0;
  float f[32];
  if constexpr (NW) {
#pragma unroll
    for (int q = 0; q < 8; ++q) {
      float4v v = *(const float4v*)(p + q * 4);
      f[q * 4 + 0] = v[0]; f[q * 4 + 1] = v[1]; f[q * 4 + 2] = v[2]; f[q * 4 + 3] = v[3];
    }
  } else {
    ld32_sys(p, f);
  }
  float s = 0.f, ss = 0.f;
#pragma unroll
  for (int i = 0; i < 32; ++i) { s += f[i]; ss += f[i] * f[i]; }
#pragma unroll
  for (int m = 1; m <= 16; m <<= 1) { s += __shfl_xor(s, m, 64); ss += __shfl_xor(ss, m, 64); }
  float mu = s * (1.f / H_);
  float var = ss * (1.f / H_) - mu * mu;
  float rs = rsqrtf(var + LNEPS);
  // permuted LN-param layout: logical 32k+c stored at 32k+((c+k)&31) -> conflict-free
#pragma unroll
  for (int c = 0; c < 32; ++c) {
    float w = lnw[c0 + ((c + k) & 31)];
    float b = lnb[c0 + ((c + k) & 31)];
    float y = (f[c] - mu) * rs * w + b;
    f[c] = tanh_fast(y);
  }
  if (cgsel >= 0 && k == cgsel) {
    float* pa = gA + (size_t)r * H_ + c0;
#pragma unroll
    for (int q = 0; q < 8; ++q) *(float4v*)(pa + q * 4) = *(const float4v*)&f[q * 4];
    if (gB) {
      float* pb = gB + (size_t)r * H_ + c0;
#pragma unroll
      for (int q = 0; q < 8; ++q) *(float4v*)(pb + q * 4) = *(const float4v*)&f[q * 4];
    }
  }
#pragma unroll
  for (int q = 0; q < 4; ++q) {
    s16x8 hi, lo;
#pragma unroll
    for (int j = 0; j < 8; ++j) { HiLo x = split1(f[q * 8 + j]); hi[j] = x.hi; lo[j] = x.lo; }
    int ix = chix(r, c0 + q * 8);
    *(s16x8*)&dh[ix] = hi; *(s16x8*)&dl[ix] = lo;
  }
}

#define MFMA(a, b, c) __builtin_amdgcn_mfma_f32_16x16x32_bf16(a, b, c, 0, 0, 0)
#define AF(buf, idx) (*(const s16x8*)&buf[chix(lane & 15, (idx) + kb8)])

template <bool NW>
__global__ __launch_bounds__(512, 1) void rnn_persist(
    const float* __restrict__ input, const float* __restrict__ hidden,
    const float* __restrict__ W_ih0, const float* __restrict__ W_hh0,
    const float* __restrict__ b_ih0, const float* __restrict__ b_hh0,
    const float* __restrict__ ln_w0, const float* __restrict__ ln_b0,
    const float* __restrict__ W_ih1, const float* __restrict__ W_hh1,
    const float* __restrict__ b_ih1, const float* __restrict__ b_hh1,
    const float* __restrict__ ln_w1, const float* __restrict__ ln_b1,
    float* gout, float* pre0, float* pre1, int* flag0, int* flag1) {
  __shared__ ushort_t sAh[16 * 1032];
  __shared__ ushort_t sAl[16 * 1032];
  __shared__ float slnw0[1024], slnb0[1024];
  __shared__ float slnw1[1024], slnb1[1024];
  __shared__ float sacc[2][3][16][16];

  const int tid = threadIdx.x;
  const int lane = tid & 63;
  const int w = tid >> 6;
  const int colt = w & 1, kh = w >> 1;
  const int blk = blockIdx.x;
  const int layer = blk >> 7;
  const int id = blk & 127;
  const int rg = id >> 5, cg = id & 31;
  const int rowbase = rg * RB;
  const int cgl = cg * 32 + colt * 16 + (lane & 15);
  const int kb8 = (lane >> 4) * 8;
  const int l15 = lane & 15;
  const int WM = NW ? (T_ - 1) : 7;  // slot mask: no-wrap vs 8-slot ring

  for (int i = tid; i < H_; i += 512) {
    int pi = (i & ~31) | ((i + (i >> 5)) & 31);
    slnw0[pi] = ln_w0[i]; slnb0[pi] = ln_b0[i];
    slnw1[pi] = ln_w1[i]; slnb1[pi] = ln_b1[i];
  }

  float bias = 0.f;

  if (layer == 0) {
    s16x8 WhiX[4], WloX[4], WhiH[8], WloH[8];
#pragma unroll
    for (int s = 0; s < 4; ++s)
      ldw8s(W_ih0 + (size_t)cgl * IN_ + kh * 128 + s * 32 + kb8, WhiX[s], WloX[s]);
#pragma unroll
    for (int s = 0; s < 8; ++s)
      ldw8s(W_hh0 + (size_t)cgl * H_ + kh * 256 + s * 32 + kb8, WhiH[s], WloH[s]);
    if (kh == 0) bias = b_ih0[cgl] + b_hh0[cgl];
    __syncthreads();

    for (int t = 0; t < T_; ++t) {
      stageX(input + ((size_t)t * B_ + rowbase) * IN_, sAh, sAl, tid);
      __syncthreads();
      f32x4 aP = (kh == 0) ? (f32x4){bias, bias, bias, bias} : (f32x4){0.f, 0.f, 0.f, 0.f};
      f32x4 aQ = {0.f, 0.f, 0.f, 0.f}, aR = {0.f, 0.f, 0.f, 0.f};
#pragma unroll
      for (int s = 0; s < 4; ++s) {
        s16x8 ah = AF(sAh, kh * 128 + s * 32), al = AF(sAl, kh * 128 + s * 32);
        aP = MFMA(ah, WhiX[s], aP); aQ = MFMA(ah, WloX[s], aQ); aR = MFMA(al, WhiX[s], aR);
      }
      if (tid == 0 && t > 0) spinR(&flag0[FIDX(t - 1, rg)], NCG);
      if (!NW) {  // back-pressure only needed when the ring wraps
        if (tid == 64 && t >= RING) spinR(&flag1[FIDX(t - RING, rg)], NCG);
      }
      __syncthreads();
      if (t == 0) stageF32(hidden + (size_t)rowbase * H_, sAh, sAl, tid);
      else stageLT<NW>(pre0 + ((size_t)((t - 1) & WM) * B_ + rowbase) * H_, sAh, sAl,
                       slnw0, slnb0, tid, -1, nullptr, nullptr);
      __syncthreads();
#pragma unroll
      for (int s = 0; s < 8; ++s) {
        s16x8 ah = AF(sAh, kh * 256 + s * 32), al = AF(sAl, kh * 256 + s * 32);
        aP = MFMA(ah, WhiH[s], aP); aQ = MFMA(ah, WloH[s], aQ); aR = MFMA(al, WhiH[s], aR);
      }
      f32x4 sum = aP + aQ + aR;
      if (kh > 0) {
#pragma unroll
        for (int j = 0; j < 4; ++j) sacc[colt][kh - 1][(lane >> 4) * 4 + j][l15] = sum[j];
      }
      __syncthreads();
      if (kh == 0) {
        float* dst = pre0 + ((size_t)(t & WM) * B_ + rowbase) * H_;
#pragma unroll
        for (int j = 0; j < 4; ++j) {
          int row = (lane >> 4) * 4 + j;
          float v = sum[j] + sacc[colt][0][row][l15] + sacc[colt][1][row][l15] +
                    sacc[colt][2][row][l15];
          st1_sys(&dst[(size_t)row * H_ + cgl], v);
        }
        relfence();
      }
      __syncthreads();
      if (tid == 0) addrel(&flag0[FIDX(t, rg)]);
    }
    // epilogue: h_fin[0] slice
    if (tid == 0) spinR(&flag0[FIDX(T_ - 1, rg)], NCG);
    __syncthreads();
    stageLT<NW>(pre0 + ((size_t)((T_ - 1) & WM) * B_ + rowbase) * H_, sAh, sAl, slnw0, slnb0,
                tid, cg, gout + (size_t)T_ * B_ * H_ + (size_t)rowbase * H_, nullptr);
  } else {
    s16x8 WhiA[8], WloA[8], WhiB[8], WloB[8];
#pragma unroll
    for (int s = 0; s < 8; ++s)
      ldw8s(W_hh1 + (size_t)cgl * H_ + kh * 256 + s * 32 + kb8, WhiA[s], WloA[s]);
#pragma unroll
    for (int s = 0; s < 8; ++s)
      ldw8s(W_ih1 + (size_t)cgl * H_ + kh * 256 + s * 32 + kb8, WhiB[s], WloB[s]);
    if (kh == 0) bias = b_ih1[cgl] + b_hh1[cgl];
    __syncthreads();

    for (int t = 0; t < T_; ++t) {
      if (tid == 0) spinR(&flag0[FIDX(t, rg)], NCG);
      if (tid == 64 && t > 0) spinR(&flag1[FIDX(t - 1, rg)], NCG);
      __syncthreads();
      // h0[t] phase (flag0[t] pre-satisfied in steady state: L0 runs ahead)
      stageLT<NW>(pre0 + ((size_t)(t & WM) * B_ + rowbase) * H_, sAh, sAl,
                  slnw0, slnb0, tid, -1, nullptr, nullptr);
      __syncthreads();
      f32x4 aP = (kh == 0) ? (f32x4){bias, bias, bias, bias} : (f32x4){0.f, 0.f, 0.f, 0.f};
      f32x4 aQ = {0.f, 0.f, 0.f, 0.f}, aR = {0.f, 0.f, 0.f, 0.f};
#pragma unroll
      for (int s = 0; s < 8; ++s) {
        s16x8 ah = AF(sAh, kh * 256 + s * 32), al = AF(sAl, kh * 256 + s * 32);
        aP = MFMA(ah, WhiB[s], aP); aQ = MFMA(ah, WloB[s], aQ); aR = MFMA(al, WhiB[s], aR);
      }
      __syncthreads();
      // h1[t-1] phase: consumer-side LN1+tanh; writes gout[t-1] slice
      if (t == 0) stageF32(hidden + (size_t)B_ * H_ + (size_t)rowbase * H_, sAh, sAl, tid);
      else stageLT<NW>(pre1 + ((size_t)((t - 1) & WM) * B_ + rowbase) * H_, sAh, sAl,
                       slnw1, slnb1, tid, cg,
                       gout + ((size_t)(t - 1) * B_ + rowbase) * H_, nullptr);
      __syncthreads();
#pragma unroll
      for (int s = 0; s < 8; ++s) {
        s16x8 ah = AF(sAh, kh * 256 + s * 32), al = AF(sAl, kh * 256 + s * 32);
        aP = MFMA(ah, WhiA[s], aP); aQ = MFMA(ah, WloA[s], aQ); aR = MFMA(al, WhiA[s], aR);
      }
      f32x4 sum = aP + aQ + aR;
      if (kh > 0) {
#pragma unroll
        for (int j = 0; j < 4; ++j) sacc[colt][kh - 1][(lane >> 4) * 4 + j][l15] = sum[j];
      }
      __syncthreads();
      if (kh == 0) {
        float* dst = pre1 + ((size_t)(t & WM) * B_ + rowbase) * H_;
#pragma unroll
        for (int j = 0; j < 4; ++j) {
          int row = (lane >> 4) * 4 + j;
          float v = sum[j] + sacc[colt][0][row][l15] + sacc[colt][1][row][l15] +
                    sacc[colt][2][row][l15];
          st1_sys(&dst[(size_t)row * H_ + cgl], v);
        }
        relfence();
      }
      __syncthreads();
      if (tid == 0) addrel(&flag1[FIDX(t, rg)]);
    }
    // epilogue: gout[T-1] + h_fin[1] slices
    if (tid == 0) spinR(&flag1[FIDX(T_ - 1, rg)], NCG);
    __syncthreads();
    stageLT<NW>(pre1 + ((size_t)((T_ - 1) & WM) * B_ + rowbase) * H_, sAh, sAl, slnw1, slnb1,
                tid, cg, gout + ((size_t)(T_ - 1) * B_ + rowbase) * H_,
                gout + (size_t)T_ * B_ * H_ + (size_t)B_ * H_ + (size_t)rowbase * H_);
  }
}

extern "C" void kernel_launch(void* const* d_in, const int* in_sizes, int n_in,
                              void* d_out, int out_size, void* d_ws, size_t ws_size,
                              hipStream_t stream) {
  const float* input = (const float*)d_in[0];
  const float* hidden = (const float*)d_in[1];
  const float* W_ih0 = (const float*)d_in[2];
  const float* W_hh0 = (const float*)d_in[3];
  const float* b_ih0 = (const float*)d_in[4];
  const float* b_hh0 = (const float*)d_in[5];
  const float* ln_w0 = (const float*)d_in[6];
  const float* ln_b0 = (const float*)d_in[7];
  const float* W_ih1 = (const float*)d_in[8];
  const float* W_hh1 = (const float*)d_in[9];
  const float* b_ih1 = (const float*)d_in[10];
  const float* b_hh1 = (const float*)d_in[11];
  const float* ln_w1 = (const float*)d_in[12];
  const float* ln_b1 = (const float*)d_in[13];
  float* gout = (float*)d_out;

  const size_t slabT = (size_t)T_ * B_ * H_ * 4;  // 128 MB per no-wrap buffer
  const size_t need_nw = 2 * slabT + 0x40000;

  char* ws = (char*)d_ws;
  if (ws_size >= need_nw) {
    float* pre0 = (float*)ws;
    float* pre1 = (float*)(ws + slabT);
    char* ctrl = ws + 2 * slabT;
    int* flag0 = (int*)ctrl;
    int* flag1 = (int*)(ctrl + 0x20000);
    (void)hipMemsetAsync(ctrl, 0, 0x40000, stream);
    hipLaunchKernelGGL(rnn_persist<true>, dim3(256), dim3(512), 0, stream,
                       input, hidden, W_ih0, W_hh0, b_ih0, b_hh0, ln_w0, ln_b0,
                       W_ih1, W_hh1, b_ih1, b_hh1, ln_w1, ln_b1,
                       gout, pre0, pre1, flag0, flag1);
  } else {
    float* pre0 = (float*)ws;                     // 2 MB ring
    float* pre1 = (float*)(ws + (2u << 20));      // 2 MB ring
    char* ctrl = ws + (4u << 20);
    int* flag0 = (int*)ctrl;
    int* flag1 = (int*)(ctrl + 0x20000);
    (void)hipMemsetAsync(ctrl, 0, 0x40000, stream);
    hipLaunchKernelGGL(rnn_persist<false>, dim3(256), dim3(512), 0, stream,
                       input, hidden, W_ih0, W_hh0, b_ih0, b_hh0, ln_w0, ln_b0,
                       W_ih1, W_hh1, b_ih1, b_hh1, ln_w1, ln_b1,
                       gout, pre0, pre1, flag0, flag1);
  }
}

// Round 8
// 9093.867 us; speedup vs baseline: 4.4485x; 1.9660x over previous
//
#include <hip/hip_runtime.h>
#include <stdint.h>

#define T_ 512
#define B_ 64
#define IN_ 512
#define H_ 1024
#define RB 16
#define LNEPS 1e-5f
#define FOFF(t, rg) ((((t) * 4 + (rg)) << 4))  // 16 ints (64B line) per (t,rg)

typedef __attribute__((ext_vector_type(8))) _Float16 h16x8;
typedef __attribute__((ext_vector_type(4))) float f32x4;
typedef __attribute__((ext_vector_type(4))) float float4v;
typedef __attribute__((ext_vector_type(4))) int int4v;
typedef unsigned short ushort_t;

__device__ __forceinline__ float tanh_fast(float y) {
  y = fminf(15.f, fmaxf(-15.f, y));
  float t = __expf(2.f * y);
  return (t - 1.f) / (t + 1.f);
}
// load 8 fp32 weights -> fp16 fragment
__device__ __forceinline__ h16x8 ldw8h(const float* p) {
  float4v a = *(const float4v*)p;
  float4v b = *(const float4v*)(p + 4);
  h16x8 o;
  o[0] = (_Float16)a[0]; o[1] = (_Float16)a[1]; o[2] = (_Float16)a[2]; o[3] = (_Float16)a[3];
  o[4] = (_Float16)b[0]; o[5] = (_Float16)b[1]; o[6] = (_Float16)b[2]; o[7] = (_Float16)b[3];
  return o;
}
#define PIN8(x) asm volatile("" : "+v"(x))

// ---- L3-direct (sc0 sc1) store path + stamp/poll sync (no RMW, no cache-wide ops) ----
__device__ __forceinline__ void st1_sys(float* p, float v) {
  asm volatile("global_store_dword %0, %1, off sc0 sc1" :: "v"(p), "v"(v) : "memory");
}
__device__ __forceinline__ void relfence() { asm volatile("s_waitcnt vmcnt(0)" ::: "memory"); }
__device__ __forceinline__ void stamp(int* p, int v) {
  asm volatile("global_store_dword %0, %1, off sc0 sc1" :: "v"(p), "v"(v) : "memory");
}
// poll 16 producer stamps (one 64B line) until min >= target
__device__ __forceinline__ void poll16(const int* p, int target) {
  int n = 0;
  while (true) {
    int4v a, b, c, d;
    asm volatile(
        "global_load_dwordx4 %0, %4, off sc0 sc1\n\t"
        "global_load_dwordx4 %1, %4, off offset:16 sc0 sc1\n\t"
        "global_load_dwordx4 %2, %4, off offset:32 sc0 sc1\n\t"
        "global_load_dwordx4 %3, %4, off offset:48 sc0 sc1\n\t"
        "s_waitcnt vmcnt(0)"
        : "=&v"(a), "=&v"(b), "=&v"(c), "=&v"(d)
        : "v"(p)
        : "memory");
    int m0 = min(min(a[0], a[1]), min(a[2], a[3]));
    int m1 = min(min(b[0], b[1]), min(b[2], b[3]));
    int m2 = min(min(c[0], c[1]), min(c[2], c[3]));
    int m3 = min(min(d[0], d[1]), min(d[2], d[3]));
    if (min(min(m0, m1), min(m2, m3)) >= target) return;
    __builtin_amdgcn_s_sleep(2);
    if (++n > 1000000) return;  // safety: wrong data instead of hang
  }
}

// LDS swizzle (half units): chunk = 8 halves (16B); fold row/owner bits into bank bits
__device__ __forceinline__ int chix(int r, int c) {
  int ch = c >> 3;
  int low = (ch ^ r ^ (ch >> 2)) & 3;
  return r * 1032 + ((((ch >> 2) << 2) | low) << 3) + (c & 7);
}

// ---- staging (512 threads; r=tid>>5 in 0..15, k=tid&31 owns cols 32k..32k+31) ----
__device__ __forceinline__ void stageHf(const float* src, ushort_t* dA, int tid) {
  int r = tid >> 5, k = tid & 31, c0 = k * 32;
  const float* p = src + (size_t)r * H_ + c0;
#pragma unroll
  for (int q = 0; q < 4; ++q) {
    float4v a = *(const float4v*)(p + q * 8);
    float4v b = *(const float4v*)(p + q * 8 + 4);
    h16x8 h;
    h[0] = (_Float16)a[0]; h[1] = (_Float16)a[1]; h[2] = (_Float16)a[2]; h[3] = (_Float16)a[3];
    h[4] = (_Float16)b[0]; h[5] = (_Float16)b[1]; h[6] = (_Float16)b[2]; h[7] = (_Float16)b[3];
    *(h16x8*)&dA[chix(r, c0 + q * 8)] = h;
  }
}
__device__ __forceinline__ void stageXh(const float* src, ushort_t* dA, int tid) {
  int r = tid >> 5, k = tid & 31, c0 = k * 16;
  const float* p = src + (size_t)r * IN_ + c0;
#pragma unroll
  for (int q = 0; q < 2; ++q) {
    float4v a = *(const float4v*)(p + q * 8);
    float4v b = *(const float4v*)(p + q * 8 + 4);
    h16x8 h;
    h[0] = (_Float16)a[0]; h[1] = (_Float16)a[1]; h[2] = (_Float16)a[2]; h[3] = (_Float16)a[3];
    h[4] = (_Float16)b[0]; h[5] = (_Float16)b[1]; h[6] = (_Float16)b[2]; h[7] = (_Float16)b[3];
    *(h16x8*)&dA[chix(r, c0 + q * 8)] = h;
  }
}
// fp32 pre rows (plain loads; write-once addresses) -> LN+tanh -> fp16 LDS;
// threads with (k>>1)==cg write fp32 rows to gA (and gB)
__device__ __forceinline__ void stageLTh(const float* src, ushort_t* dA,
                                         const float* lnw, const float* lnb, int tid,
                                         int cg, bool wr, float* gA, float* gB) {
  int r = tid >> 5, k = tid & 31, c0 = k * 32;
  const float* p = src + (size_t)r * H_ + c0;
  float f[32];
#pragma unroll
  for (int q = 0; q < 8; ++q) {
    float4v v = *(const float4v*)(p + q * 4);
    f[q * 4 + 0] = v[0]; f[q * 4 + 1] = v[1]; f[q * 4 + 2] = v[2]; f[q * 4 + 3] = v[3];
  }
  float s = 0.f, ss = 0.f;
#pragma unroll
  for (int i = 0; i < 32; ++i) { s += f[i]; ss += f[i] * f[i]; }
#pragma unroll
  for (int m = 1; m <= 16; m <<= 1) { s += __shfl_xor(s, m, 64); ss += __shfl_xor(ss, m, 64); }
  float mu = s * (1.f / H_);
  float var = ss * (1.f / H_) - mu * mu;
  float rs = rsqrtf(var + LNEPS);
  // permuted LN-param layout: logical 32k+c stored at 32k+((c+k)&31) -> conflict-free
#pragma unroll
  for (int c = 0; c < 32; ++c) {
    float w = lnw[c0 + ((c + k) & 31)];
    float b = lnb[c0 + ((c + k) & 31)];
    f[c] = tanh_fast((f[c] - mu) * rs * w + b);
  }
  if (wr && (k >> 1) == cg) {
    float* pa = gA + (size_t)r * H_ + c0;
#pragma unroll
    for (int q = 0; q < 8; ++q) *(float4v*)(pa + q * 4) = *(const float4v*)&f[q * 4];
    if (gB) {
      float* pb = gB + (size_t)r * H_ + c0;
#pragma unroll
      for (int q = 0; q < 8; ++q) *(float4v*)(pb + q * 4) = *(const float4v*)&f[q * 4];
    }
  }
#pragma unroll
  for (int q = 0; q < 4; ++q) {
    h16x8 h;
#pragma unroll
    for (int j = 0; j < 8; ++j) h[j] = (_Float16)f[q * 8 + j];
    *(h16x8*)&dA[chix(r, c0 + q * 8)] = h;
  }
}

#define MFMA(a, b, c) __builtin_amdgcn_mfma_f32_16x16x32_f16(a, b, c, 0, 0, 0)
#define AF(idx) (*(const h16x8*)&sA[chix(lane & 15, (idx) + kb8)])

// geometry: 512 thr = 8 waves = 4 colt x 2 kh; block owns 64 cols; 16 cg x 4 rg per layer
__global__ __launch_bounds__(512, 1) void rnn_persist(
    const float* __restrict__ input, const float* __restrict__ hidden,
    const float* __restrict__ W_ih0, const float* __restrict__ W_hh0,
    const float* __restrict__ b_ih0, const float* __restrict__ b_hh0,
    const float* __restrict__ ln_w0, const float* __restrict__ ln_b0,
    const float* __restrict__ W_ih1, const float* __restrict__ W_hh1,
    const float* __restrict__ b_ih1, const float* __restrict__ b_hh1,
    const float* __restrict__ ln_w1, const float* __restrict__ ln_b1,
    float* gout, float* pre0, float* pre1, int* flag0, int* flag1) {
  __shared__ ushort_t sA[16 * 1032];
  __shared__ float slnw0[1024], slnb0[1024];
  __shared__ float slnw1[1024], slnb1[1024];
  __shared__ float sacc[4][16][16];

  const int tid = threadIdx.x;
  const int lane = tid & 63;
  const int w = tid >> 6;
  const int colt = w & 3, kh = w >> 2;  // 4 col-tiles x 2 K-halves
  const int blk = blockIdx.x;
  const int layer = blk >> 6;
  const int id = blk & 63;
  const int rg = id >> 4, cg = id & 15;
  const int rowbase = rg * RB;
  const int cgl = cg * 64 + colt * 16 + (lane & 15);
  const int kb8 = (lane >> 4) * 8;
  const int l15 = lane & 15;

  for (int i = tid; i < H_; i += 512) {
    int pi = (i & ~31) | ((i + (i >> 5)) & 31);
    slnw0[pi] = ln_w0[i]; slnb0[pi] = ln_b0[i];
    slnw1[pi] = ln_w1[i]; slnb1[pi] = ln_b1[i];
  }

  float bias = 0.f;

  if (layer == 0) {
    // weights: W_ih0 kh-slice K=256 (8 frags) + W_hh0 kh-slice K=512 (16 frags), fp16
    h16x8 WX[8], WH[16];
#pragma unroll
    for (int s = 0; s < 8; ++s) {
      WX[s] = ldw8h(W_ih0 + (size_t)cgl * IN_ + kh * 256 + s * 32 + kb8);
      PIN8(WX[s]);
    }
#pragma unroll
    for (int s = 0; s < 16; ++s) {
      WH[s] = ldw8h(W_hh0 + (size_t)cgl * H_ + kh * 512 + s * 32 + kb8);
      PIN8(WH[s]);
    }
    if (kh == 0) bias = b_ih0[cgl] + b_hh0[cgl];
    __syncthreads();

    for (int t = 0; t < T_; ++t) {
      stageXh(input + ((size_t)t * B_ + rowbase) * IN_, sA, tid);
      __syncthreads();
      f32x4 acc = (kh == 0) ? (f32x4){bias, bias, bias, bias} : (f32x4){0.f, 0.f, 0.f, 0.f};
#pragma unroll
      for (int s = 0; s < 8; ++s) acc = MFMA(AF(kh * 256 + s * 32), WX[s], acc);
      if (tid == 0 && t > 0) poll16(&flag0[FOFF(t - 1, rg)], t);
      __syncthreads();
      if (t == 0) stageHf(hidden + (size_t)rowbase * H_, sA, tid);
      else stageLTh(pre0 + ((size_t)(t - 1) * B_ + rowbase) * H_, sA,
                    slnw0, slnb0, tid, cg, false, nullptr, nullptr);
      __syncthreads();
#pragma unroll
      for (int s = 0; s < 16; ++s) acc = MFMA(AF(kh * 512 + s * 32), WH[s], acc);
      if (kh == 1) {
#pragma unroll
        for (int j = 0; j < 4; ++j) sacc[colt][(lane >> 4) * 4 + j][l15] = acc[j];
      }
      __syncthreads();
      if (kh == 0) {
        float* dst = pre0 + ((size_t)t * B_ + rowbase) * H_;
#pragma unroll
        for (int j = 0; j < 4; ++j) {
          int row = (lane >> 4) * 4 + j;
          st1_sys(&dst[(size_t)row * H_ + cgl], acc[j] + sacc[colt][row][l15]);
        }
        relfence();
      }
      __syncthreads();
      if (tid == 0) stamp(&flag0[FOFF(t, rg) + cg], t + 1);
    }
    // epilogue: h_fin[0] slice
    if (tid == 0) poll16(&flag0[FOFF(T_ - 1, rg)], T_);
    __syncthreads();
    stageLTh(pre0 + ((size_t)(T_ - 1) * B_ + rowbase) * H_, sA, slnw0, slnb0, tid, cg, true,
             gout + (size_t)T_ * B_ * H_ + (size_t)rowbase * H_, nullptr);
  } else {
    // weights: W_ih1 + W_hh1 kh-slices K=512 each (16+16 frags), fp16
    h16x8 WB[16], WA[16];
#pragma unroll
    for (int s = 0; s < 16; ++s) {
      WB[s] = ldw8h(W_ih1 + (size_t)cgl * H_ + kh * 512 + s * 32 + kb8);
      PIN8(WB[s]);
    }
#pragma unroll
    for (int s = 0; s < 16; ++s) {
      WA[s] = ldw8h(W_hh1 + (size_t)cgl * H_ + kh * 512 + s * 32 + kb8);
      PIN8(WA[s]);
    }
    if (kh == 0) bias = b_ih1[cgl] + b_hh1[cgl];
    __syncthreads();

    for (int t = 0; t < T_; ++t) {
      if (tid == 0) poll16(&flag0[FOFF(t, rg)], t + 1);  // h0[t] ready (L0 runs ahead)
      __syncthreads();
      stageLTh(pre0 + ((size_t)t * B_ + rowbase) * H_, sA,
               slnw0, slnb0, tid, cg, false, nullptr, nullptr);
      __syncthreads();
      f32x4 acc = (kh == 0) ? (f32x4){bias, bias, bias, bias} : (f32x4){0.f, 0.f, 0.f, 0.f};
#pragma unroll
      for (int s = 0; s < 16; ++s) acc = MFMA(AF(kh * 512 + s * 32), WB[s], acc);
      if (tid == 0 && t > 0) poll16(&flag1[FOFF(t - 1, rg)], t);  // own-layer chain
      __syncthreads();
      if (t == 0) stageHf(hidden + (size_t)B_ * H_ + (size_t)rowbase * H_, sA, tid);
      else stageLTh(pre1 + ((size_t)(t - 1) * B_ + rowbase) * H_, sA,
                    slnw1, slnb1, tid, cg, true,
                    gout + ((size_t)(t - 1) * B_ + rowbase) * H_, nullptr);
      __syncthreads();
#pragma unroll
      for (int s = 0; s < 16; ++s) acc = MFMA(AF(kh * 512 + s * 32), WA[s], acc);
      if (kh == 1) {
#pragma unroll
        for (int j = 0; j < 4; ++j) sacc[colt][(lane >> 4) * 4 + j][l15] = acc[j];
      }
      __syncthreads();
      if (kh == 0) {
        float* dst = pre1 + ((size_t)t * B_ + rowbase) * H_;
#pragma unroll
        for (int j = 0; j < 4; ++j) {
          int row = (lane >> 4) * 4 + j;
          st1_sys(&dst[(size_t)row * H_ + cgl], acc[j] + sacc[colt][row][l15]);
        }
        relfence();
      }
      __syncthreads();
      if (tid == 0) stamp(&flag1[FOFF(t, rg) + cg], t + 1);
    }
    // epilogue: gout[T-1] + h_fin[1] slices
    if (tid == 0) poll16(&flag1[FOFF(T_ - 1, rg)], T_);
    __syncthreads();
    stageLTh(pre1 + ((size_t)(T_ - 1) * B_ + rowbase) * H_, sA, slnw1, slnb1, tid, cg, true,
             gout + ((size_t)(T_ - 1) * B_ + rowbase) * H_,
             gout + (size_t)T_ * B_ * H_ + (size_t)B_ * H_ + (size_t)rowbase * H_);
  }
}

extern "C" void kernel_launch(void* const* d_in, const int* in_sizes, int n_in,
                              void* d_out, int out_size, void* d_ws, size_t ws_size,
                              hipStream_t stream) {
  const float* input = (const float*)d_in[0];
  const float* hidden = (const float*)d_in[1];
  const float* W_ih0 = (const float*)d_in[2];
  const float* W_hh0 = (const float*)d_in[3];
  const float* b_ih0 = (const float*)d_in[4];
  const float* b_hh0 = (const float*)d_in[5];
  const float* ln_w0 = (const float*)d_in[6];
  const float* ln_b0 = (const float*)d_in[7];
  const float* W_ih1 = (const float*)d_in[8];
  const float* W_hh1 = (const float*)d_in[9];
  const float* b_ih1 = (const float*)d_in[10];
  const float* b_hh1 = (const float*)d_in[11];
  const float* ln_w1 = (const float*)d_in[12];
  const float* ln_b1 = (const float*)d_in[13];
  float* gout = (float*)d_out;

  const size_t slabT = (size_t)T_ * B_ * H_ * 4;  // 128 MB per no-wrap buffer
  char* ws = (char*)d_ws;
  float* pre0 = (float*)ws;
  float* pre1 = (float*)(ws + slabT);
  char* ctrl = ws + 2 * slabT;
  int* flag0 = (int*)ctrl;                   // 512*4*16*4 = 128 KB
  int* flag1 = (int*)(ctrl + 0x20000);       // 128 KB

  (void)hipMemsetAsync(ctrl, 0, 0x40000, stream);
  hipLaunchKernelGGL(rnn_persist, dim3(128), dim3(512), 0, stream,
                     input, hidden, W_ih0, W_hh0, b_ih0, b_hh0, ln_w0, ln_b0,
                     W_ih1, W_hh1, b_ih1, b_hh1, ln_w1, ln_b1,
                     gout, pre0, pre1, flag0, flag1);
}

// Round 9
// 8055.670 us; speedup vs baseline: 5.0218x; 1.1289x over previous
//
#include <hip/hip_runtime.h>
#include <stdint.h>

#define T_ 512
#define B_ 64
#define IN_ 512
#define H_ 1024
#define RB 16
#define LNEPS 1e-5f
#define FL(t, rg) (((t) * 4 + (rg)) * 32)  // ushort index: 64B-strided line, 16 u16 stamps used

typedef __attribute__((ext_vector_type(8))) _Float16 h16x8;
typedef __attribute__((ext_vector_type(4))) float f32x4;
typedef __attribute__((ext_vector_type(4))) float float4v;
typedef __attribute__((ext_vector_type(4))) int int4v;
typedef unsigned short ushort_t;

__device__ __forceinline__ float tanh_fast(float y) {
  y = fminf(15.f, fmaxf(-15.f, y));
  float t = __expf(2.f * y);
  return (t - 1.f) / (t + 1.f);
}
__device__ __forceinline__ h16x8 ldw8h(const float* p) {
  float4v a = *(const float4v*)p;
  float4v b = *(const float4v*)(p + 4);
  h16x8 o;
  o[0] = (_Float16)a[0]; o[1] = (_Float16)a[1]; o[2] = (_Float16)a[2]; o[3] = (_Float16)a[3];
  o[4] = (_Float16)b[0]; o[5] = (_Float16)b[1]; o[6] = (_Float16)b[2]; o[7] = (_Float16)b[3];
  return o;
}
#define PIN8(x) asm volatile("" : "+v"(x))

// ---- L3-direct (sc0 sc1) stores + u16 stamp/poll sync (no RMW, no cache-wide ops) ----
__device__ __forceinline__ void st1_sys(float* p, float v) {
  asm volatile("global_store_dword %0, %1, off sc0 sc1" :: "v"(p), "v"(v) : "memory");
}
__device__ __forceinline__ void relfence() { asm volatile("s_waitcnt vmcnt(0)" ::: "memory"); }
__device__ __forceinline__ void stamp16(ushort_t* p, int v) {
  asm volatile("global_store_short %0, %1, off sc0 sc1" :: "v"(p), "v"(v) : "memory");
}
// poll one 32B line (16 u16 stamps) until min >= target
__device__ __forceinline__ void poll16h(const ushort_t* p, int target) {
  int n = 0;
  while (true) {
    int4v a, b;
    asm volatile(
        "global_load_dwordx4 %0, %2, off sc0 sc1\n\t"
        "global_load_dwordx4 %1, %2, off offset:16 sc0 sc1\n\t"
        "s_waitcnt vmcnt(0)"
        : "=&v"(a), "=&v"(b) : "v"(p) : "memory");
    int mn = 0xFFFF;
#pragma unroll
    for (int i = 0; i < 4; ++i) {
      unsigned u = (unsigned)a[i], v = (unsigned)b[i];
      mn = min(mn, (int)(u & 0xFFFFu)); mn = min(mn, (int)(u >> 16));
      mn = min(mn, (int)(v & 0xFFFFu)); mn = min(mn, (int)(v >> 16));
    }
    if (mn >= target) return;
    if (n < 4) __builtin_amdgcn_s_sleep(1);
    else __builtin_amdgcn_s_sleep(4);
    if (++n > 2000000) return;  // safety: wrong data instead of hang
  }
}

// LDS swizzle (half units): chunk = 8 halves (16B); fold row/owner bits into bank bits
__device__ __forceinline__ int chix(int r, int c) {
  int ch = c >> 3;
  int low = (ch ^ r ^ (ch >> 2)) & 3;
  return r * 1032 + ((((ch >> 2) << 2) | low) << 3) + (c & 7);
}

// ---- staging: 1024 threads; wave w = row r, lane k owns cols [16k,16k+16) (or 8 for x) ----
__device__ __forceinline__ void stageHf(const float* src, ushort_t* dA, int r, int k) {
  int c0 = k * 16;
  const float* p = src + (size_t)r * H_ + c0;
  float f[16];
#pragma unroll
  for (int q = 0; q < 4; ++q) {
    float4v v = *(const float4v*)(p + q * 4);
    f[q * 4 + 0] = v[0]; f[q * 4 + 1] = v[1]; f[q * 4 + 2] = v[2]; f[q * 4 + 3] = v[3];
  }
#pragma unroll
  for (int q = 0; q < 2; ++q) {
    h16x8 h;
#pragma unroll
    for (int j = 0; j < 8; ++j) h[j] = (_Float16)f[q * 8 + j];
    *(h16x8*)&dA[chix(r, c0 + q * 8)] = h;
  }
}
__device__ __forceinline__ void stageXh(const float* src, ushort_t* dA, int r, int k) {
  int c0 = k * 8;
  const float* p = src + (size_t)r * IN_ + c0;
  float4v a = *(const float4v*)p;
  float4v b = *(const float4v*)(p + 4);
  h16x8 h;
  h[0] = (_Float16)a[0]; h[1] = (_Float16)a[1]; h[2] = (_Float16)a[2]; h[3] = (_Float16)a[3];
  h[4] = (_Float16)b[0]; h[5] = (_Float16)b[1]; h[6] = (_Float16)b[2]; h[7] = (_Float16)b[3];
  *(h16x8*)&dA[chix(r, c0)] = h;
}
// fp32 pre row (plain loads; write-once addresses) -> LN+tanh -> fp16 LDS;
// if wr, lanes with (k>>2)==cg write fp32 cols [64cg,64cg+64) to gA (and gB)
__device__ __forceinline__ void stageLTh(const float* src, ushort_t* dA,
                                         const float* lnw, const float* lnb,
                                         int r, int k, int cg, bool wr, float* gA, float* gB) {
  int c0 = k * 16;
  const float* p = src + (size_t)r * H_ + c0;
  float f[16];
#pragma unroll
  for (int q = 0; q < 4; ++q) {
    float4v v = *(const float4v*)(p + q * 4);
    f[q * 4 + 0] = v[0]; f[q * 4 + 1] = v[1]; f[q * 4 + 2] = v[2]; f[q * 4 + 3] = v[3];
  }
  float s = 0.f, ss = 0.f;
#pragma unroll
  for (int i = 0; i < 16; ++i) { s += f[i]; ss += f[i] * f[i]; }
#pragma unroll
  for (int m = 1; m <= 32; m <<= 1) { s += __shfl_xor(s, m, 64); ss += __shfl_xor(ss, m, 64); }
  float mu = s * (1.f / H_);
  float var = ss * (1.f / H_) - mu * mu;
  float rs = rsqrtf(var + LNEPS);
  // permuted LN-param layout: logical 16k+c stored at 16k+((c+k)&15)
#pragma unroll
  for (int c = 0; c < 16; ++c) {
    float w = lnw[c0 + ((c + k) & 15)];
    float b = lnb[c0 + ((c + k) & 15)];
    f[c] = tanh_fast((f[c] - mu) * rs * w + b);
  }
  if (wr && (k >> 2) == cg) {
    float* pa = gA + (size_t)r * H_ + c0;
#pragma unroll
    for (int q = 0; q < 4; ++q) *(float4v*)(pa + q * 4) = *(const float4v*)&f[q * 4];
    if (gB) {
      float* pb = gB + (size_t)r * H_ + c0;
#pragma unroll
      for (int q = 0; q < 4; ++q) *(float4v*)(pb + q * 4) = *(const float4v*)&f[q * 4];
    }
  }
#pragma unroll
  for (int q = 0; q < 2; ++q) {
    h16x8 h;
#pragma unroll
    for (int j = 0; j < 8; ++j) h[j] = (_Float16)f[q * 8 + j];
    *(h16x8*)&dA[chix(r, c0 + q * 8)] = h;
  }
}

#define MFMA(a, b, c) __builtin_amdgcn_mfma_f32_16x16x32_f16(a, b, c, 0, 0, 0)
#define AF(idx) (*(const h16x8*)&sA[chix(lane & 15, (idx) + kb8)])

// geometry: 1024 thr = 16 waves = 4 colt x 4 kh; block owns 64 cols x 16 rows
__global__ __launch_bounds__(1024, 1) void rnn_persist(
    const float* __restrict__ input, const float* __restrict__ hidden,
    const float* __restrict__ W_ih0, const float* __restrict__ W_hh0,
    const float* __restrict__ b_ih0, const float* __restrict__ b_hh0,
    const float* __restrict__ ln_w0, const float* __restrict__ ln_b0,
    const float* __restrict__ W_ih1, const float* __restrict__ W_hh1,
    const float* __restrict__ b_ih1, const float* __restrict__ b_hh1,
    const float* __restrict__ ln_w1, const float* __restrict__ ln_b1,
    float* gout, float* pre0, float* pre1,
    ushort_t* flag0a, ushort_t* flag0b, ushort_t* flag1a) {
  __shared__ ushort_t sA[16 * 1032];
  __shared__ float slnw0[1024], slnb0[1024];
  __shared__ float slnw1[1024], slnb1[1024];
  __shared__ float sacc[3][4][16][16];

  const int tid = threadIdx.x;
  const int lane = tid & 63;
  const int w = tid >> 6;
  const int colt = w & 3, kh = w >> 2;  // 4 col-tiles x 4 K-quarters
  const int blk = blockIdx.x;
  const int layer = blk >> 6;
  const int id = blk & 63;
  const int rg = id >> 4, cg = id & 15;
  const int rowbase = rg * RB;
  const int cgl = cg * 64 + colt * 16 + (lane & 15);
  const int kb8 = (lane >> 4) * 8;
  const int l15 = lane & 15;

  {  // LN params, permuted layout; 1024 threads load 1 elem each
    int i = tid;
    int pi = (i & ~15) | ((i + (i >> 4)) & 15);
    slnw0[pi] = ln_w0[i]; slnb0[pi] = ln_b0[i];
    slnw1[pi] = ln_w1[i]; slnb1[pi] = ln_b1[i];
  }

  float bias = 0.f;

  if (layer == 0) {
    // per-wave weights: W_ih0 K=128 slice (4 frags) + W_hh0 K=256 slice (8 frags) = 48 VGPR
    h16x8 WX[4], WH[8];
#pragma unroll
    for (int s = 0; s < 4; ++s) {
      WX[s] = ldw8h(W_ih0 + (size_t)cgl * IN_ + kh * 128 + s * 32 + kb8);
      PIN8(WX[s]);
    }
#pragma unroll
    for (int s = 0; s < 8; ++s) {
      WH[s] = ldw8h(W_hh0 + (size_t)cgl * H_ + kh * 256 + s * 32 + kb8);
      PIN8(WH[s]);
    }
    if (kh == 0) bias = b_ih0[cgl] + b_hh0[cgl];
    __syncthreads();

    for (int t = 0; t < T_; ++t) {
      stageXh(input + ((size_t)t * B_ + rowbase) * IN_, sA, w, lane);
      __syncthreads();
      f32x4 acc = (kh == 0) ? (f32x4){bias, bias, bias, bias} : (f32x4){0.f, 0.f, 0.f, 0.f};
#pragma unroll
      for (int s = 0; s < 4; ++s) acc = MFMA(AF(kh * 128 + s * 32), WX[s], acc);
      if (tid == 0 && t > 0) poll16h(&flag0a[FL(t - 1, rg)], t);
      __syncthreads();
      if (t == 0) stageHf(hidden + (size_t)rowbase * H_, sA, w, lane);
      else stageLTh(pre0 + ((size_t)(t - 1) * B_ + rowbase) * H_, sA,
                    slnw0, slnb0, w, lane, cg, false, nullptr, nullptr);
      __syncthreads();
#pragma unroll
      for (int s = 0; s < 8; ++s) acc = MFMA(AF(kh * 256 + s * 32), WH[s], acc);
      if (kh > 0) {
#pragma unroll
        for (int j = 0; j < 4; ++j) sacc[kh - 1][colt][(lane >> 4) * 4 + j][l15] = acc[j];
      }
      __syncthreads();
      if (kh == 0) {
        float* dst = pre0 + ((size_t)t * B_ + rowbase) * H_;
#pragma unroll
        for (int j = 0; j < 4; ++j) {
          int row = (lane >> 4) * 4 + j;
          float v = acc[j] + sacc[0][colt][row][l15] + sacc[1][colt][row][l15] +
                    sacc[2][colt][row][l15];
          st1_sys(&dst[(size_t)row * H_ + cgl], v);
        }
        relfence();
      }
      __syncthreads();
      if (tid == 0) {
        stamp16(&flag0a[FL(t, rg) + cg], t + 1);  // line for L0 pollers
        stamp16(&flag0b[FL(t, rg) + cg], t + 1);  // replica for L1 pollers
      }
    }
    // epilogue: h_fin[0] slice
    if (tid == 0) poll16h(&flag0a[FL(T_ - 1, rg)], T_);
    __syncthreads();
    stageLTh(pre0 + ((size_t)(T_ - 1) * B_ + rowbase) * H_, sA, slnw0, slnb0, w, lane, cg, true,
             gout + (size_t)T_ * B_ * H_ + (size_t)rowbase * H_, nullptr);
  } else {
    // per-wave weights: W_ih1 + W_hh1 K=256 slices (8+8 frags) = 64 VGPR
    h16x8 WB[8], WA[8];
#pragma unroll
    for (int s = 0; s < 8; ++s) {
      WB[s] = ldw8h(W_ih1 + (size_t)cgl * H_ + kh * 256 + s * 32 + kb8);
      PIN8(WB[s]);
    }
#pragma unroll
    for (int s = 0; s < 8; ++s) {
      WA[s] = ldw8h(W_hh1 + (size_t)cgl * H_ + kh * 256 + s * 32 + kb8);
      PIN8(WA[s]);
    }
    if (kh == 0) bias = b_ih1[cgl] + b_hh1[cgl];
    __syncthreads();

    for (int t = 0; t < T_; ++t) {
      if (tid == 0) poll16h(&flag0b[FL(t, rg)], t + 1);  // h0[t] ready (L0 runs ahead)
      __syncthreads();
      stageLTh(pre0 + ((size_t)t * B_ + rowbase) * H_, sA,
               slnw0, slnb0, w, lane, cg, false, nullptr, nullptr);
      __syncthreads();
      f32x4 acc = (kh == 0) ? (f32x4){bias, bias, bias, bias} : (f32x4){0.f, 0.f, 0.f, 0.f};
#pragma unroll
      for (int s = 0; s < 8; ++s) acc = MFMA(AF(kh * 256 + s * 32), WB[s], acc);
      if (tid == 0 && t > 0) poll16h(&flag1a[FL(t - 1, rg)], t);  // own-layer chain
      __syncthreads();
      if (t == 0) stageHf(hidden + (size_t)B_ * H_ + (size_t)rowbase * H_, sA, w, lane);
      else stageLTh(pre1 + ((size_t)(t - 1) * B_ + rowbase) * H_, sA,
                    slnw1, slnb1, w, lane, cg, true,
                    gout + ((size_t)(t - 1) * B_ + rowbase) * H_, nullptr);
      __syncthreads();
#pragma unroll
      for (int s = 0; s < 8; ++s) acc = MFMA(AF(kh * 256 + s * 32), WA[s], acc);
      if (kh > 0) {
#pragma unroll
        for (int j = 0; j < 4; ++j) sacc[kh - 1][colt][(lane >> 4) * 4 + j][l15] = acc[j];
      }
      __syncthreads();
      if (kh == 0) {
        float* dst = pre1 + ((size_t)t * B_ + rowbase) * H_;
#pragma unroll
        for (int j = 0; j < 4; ++j) {
          int row = (lane >> 4) * 4 + j;
          float v = acc[j] + sacc[0][colt][row][l15] + sacc[1][colt][row][l15] +
                    sacc[2][colt][row][l15];
          st1_sys(&dst[(size_t)row * H_ + cgl], v);
        }
        relfence();
      }
      __syncthreads();
      if (tid == 0) stamp16(&flag1a[FL(t, rg) + cg], t + 1);
    }
    // epilogue: gout[T-1] + h_fin[1] slices
    if (tid == 0) poll16h(&flag1a[FL(T_ - 1, rg)], T_);
    __syncthreads();
    stageLTh(pre1 + ((size_t)(T_ - 1) * B_ + rowbase) * H_, sA, slnw1, slnb1, w, lane, cg, true,
             gout + ((size_t)(T_ - 1) * B_ + rowbase) * H_,
             gout + (size_t)T_ * B_ * H_ + (size_t)B_ * H_ + (size_t)rowbase * H_);
  }
}

extern "C" void kernel_launch(void* const* d_in, const int* in_sizes, int n_in,
                              void* d_out, int out_size, void* d_ws, size_t ws_size,
                              hipStream_t stream) {
  const float* input = (const float*)d_in[0];
  const float* hidden = (const float*)d_in[1];
  const float* W_ih0 = (const float*)d_in[2];
  const float* W_hh0 = (const float*)d_in[3];
  const float* b_ih0 = (const float*)d_in[4];
  const float* b_hh0 = (const float*)d_in[5];
  const float* ln_w0 = (const float*)d_in[6];
  const float* ln_b0 = (const float*)d_in[7];
  const float* W_ih1 = (const float*)d_in[8];
  const float* W_hh1 = (const float*)d_in[9];
  const float* b_ih1 = (const float*)d_in[10];
  const float* b_hh1 = (const float*)d_in[11];
  const float* ln_w1 = (const float*)d_in[12];
  const float* ln_b1 = (const float*)d_in[13];
  float* gout = (float*)d_out;

  const size_t slabT = (size_t)T_ * B_ * H_ * 4;  // 128 MB per no-wrap buffer
  char* ws = (char*)d_ws;
  float* pre0 = (float*)ws;
  float* pre1 = (float*)(ws + slabT);
  char* ctrl = ws + 2 * slabT;
  ushort_t* flag0a = (ushort_t*)ctrl;                  // 2048 lines x 64B = 128 KB
  ushort_t* flag0b = (ushort_t*)(ctrl + 0x20000);      // 128 KB
  ushort_t* flag1a = (ushort_t*)(ctrl + 0x40000);      // 128 KB

  (void)hipMemsetAsync(ctrl, 0, 0x60000, stream);
  hipLaunchKernelGGL(rnn_persist, dim3(128), dim3(1024), 0, stream,
                     input, hidden, W_ih0, W_hh0, b_ih0, b_hh0, ln_w0, ln_b0,
                     W_ih1, W_hh1, b_ih1, b_hh1, ln_w1, ln_b1,
                     gout, pre0, pre1, flag0a, flag0b, flag1a);
}

// Round 10
// 6800.578 us; speedup vs baseline: 5.9486x; 1.1846x over previous
//
#include <hip/hip_runtime.h>
#include <stdint.h>

#define T_ 512
#define B_ 64
#define IN_ 512
#define H_ 1024
#define RB 16
#define LNEPS 1e-5f
#define FL(t, rg) (((t) * 4 + (rg)) * 32)  // ushort index: 64B line, 32 u16 stamps

typedef __attribute__((ext_vector_type(8))) _Float16 h16x8;
typedef __attribute__((ext_vector_type(4))) float f32x4;
typedef __attribute__((ext_vector_type(4))) float float4v;
typedef __attribute__((ext_vector_type(4))) int int4v;
typedef unsigned short ushort_t;

__device__ __forceinline__ float tanh_fast(float y) {
  y = fminf(15.f, fmaxf(-15.f, y));
  float t = __expf(2.f * y);
  return (t - 1.f) / (t + 1.f);
}
__device__ __forceinline__ h16x8 ldw8h(const float* p) {
  float4v a = *(const float4v*)p;
  float4v b = *(const float4v*)(p + 4);
  h16x8 o;
  o[0] = (_Float16)a[0]; o[1] = (_Float16)a[1]; o[2] = (_Float16)a[2]; o[3] = (_Float16)a[3];
  o[4] = (_Float16)b[0]; o[5] = (_Float16)b[1]; o[6] = (_Float16)b[2]; o[7] = (_Float16)b[3];
  return o;
}
#define PIN8(x) asm volatile("" : "+v"(x))

// ---- L3-direct (sc0 sc1) stores + u16 stamp/poll sync (no RMW, no cache-wide ops) ----
__device__ __forceinline__ void st1_sys(float* p, float v) {
  asm volatile("global_store_dword %0, %1, off sc0 sc1" :: "v"(p), "v"(v) : "memory");
}
__device__ __forceinline__ void relfence() { asm volatile("s_waitcnt vmcnt(0)" ::: "memory"); }
__device__ __forceinline__ void stamp16(ushort_t* p, int v) {
  asm volatile("global_store_short %0, %1, off sc0 sc1" :: "v"(p), "v"(v) : "memory");
}
// poll one 64B line (32 u16 stamps) until min >= target
__device__ __forceinline__ void poll32h(const ushort_t* p, int target) {
  int n = 0;
  while (true) {
    int4v a, b, c, d;
    asm volatile(
        "global_load_dwordx4 %0, %4, off sc0 sc1\n\t"
        "global_load_dwordx4 %1, %4, off offset:16 sc0 sc1\n\t"
        "global_load_dwordx4 %2, %4, off offset:32 sc0 sc1\n\t"
        "global_load_dwordx4 %3, %4, off offset:48 sc0 sc1\n\t"
        "s_waitcnt vmcnt(0)"
        : "=&v"(a), "=&v"(b), "=&v"(c), "=&v"(d) : "v"(p) : "memory");
    int mn = 0xFFFF;
#pragma unroll
    for (int i = 0; i < 4; ++i) {
      unsigned u0 = (unsigned)a[i], u1 = (unsigned)b[i], u2 = (unsigned)c[i], u3 = (unsigned)d[i];
      mn = min(mn, (int)(u0 & 0xFFFFu)); mn = min(mn, (int)(u0 >> 16));
      mn = min(mn, (int)(u1 & 0xFFFFu)); mn = min(mn, (int)(u1 >> 16));
      mn = min(mn, (int)(u2 & 0xFFFFu)); mn = min(mn, (int)(u2 >> 16));
      mn = min(mn, (int)(u3 & 0xFFFFu)); mn = min(mn, (int)(u3 >> 16));
    }
    if (mn >= target) return;
    if (n < 4) __builtin_amdgcn_s_sleep(1);
    else __builtin_amdgcn_s_sleep(4);
    if (++n > 2000000) return;  // safety: wrong data instead of hang
  }
}

// LDS swizzle (half units): chunk = 8 halves (16B); fold row/owner bits into bank bits
__device__ __forceinline__ int chix(int r, int c) {
  int ch = c >> 3;
  int low = (ch ^ r ^ (ch >> 2)) & 3;
  return r * 1032 + ((((ch >> 2) << 2) | low) << 3) + (c & 7);
}

// ---- staging: 512 threads; r=tid>>5 in 0..15, k=tid&31 owns cols [32k,32k+32) ----
__device__ __forceinline__ void stageHf(const float* src, ushort_t* dA, int tid) {
  int r = tid >> 5, k = tid & 31, c0 = k * 32;
  const float* p = src + (size_t)r * H_ + c0;
#pragma unroll
  for (int q = 0; q < 4; ++q) {
    float4v a = *(const float4v*)(p + q * 8);
    float4v b = *(const float4v*)(p + q * 8 + 4);
    h16x8 h;
    h[0] = (_Float16)a[0]; h[1] = (_Float16)a[1]; h[2] = (_Float16)a[2]; h[3] = (_Float16)a[3];
    h[4] = (_Float16)b[0]; h[5] = (_Float16)b[1]; h[6] = (_Float16)b[2]; h[7] = (_Float16)b[3];
    *(h16x8*)&dA[chix(r, c0 + q * 8)] = h;
  }
}
__device__ __forceinline__ void stageXh(const float* src, ushort_t* dA, int tid) {
  int r = tid >> 5, k = tid & 31, c0 = k * 16;
  const float* p = src + (size_t)r * IN_ + c0;
#pragma unroll
  for (int q = 0; q < 2; ++q) {
    float4v a = *(const float4v*)(p + q * 8);
    float4v b = *(const float4v*)(p + q * 8 + 4);
    h16x8 h;
    h[0] = (_Float16)a[0]; h[1] = (_Float16)a[1]; h[2] = (_Float16)a[2]; h[3] = (_Float16)a[3];
    h[4] = (_Float16)b[0]; h[5] = (_Float16)b[1]; h[6] = (_Float16)b[2]; h[7] = (_Float16)b[3];
    *(h16x8*)&dA[chix(r, c0 + q * 8)] = h;
  }
}
// fp32 pre rows (plain loads; write-once addresses) -> LN+tanh -> fp16 LDS;
// if wr, thread k==cg writes its fp32 cols [32cg,32cg+32) to gA (and gB)
__device__ __forceinline__ void stageLTh(const float* src, ushort_t* dA,
                                         const float* lnw, const float* lnb, int tid,
                                         int cg, bool wr, float* gA, float* gB) {
  int r = tid >> 5, k = tid & 31, c0 = k * 32;
  const float* p = src + (size_t)r * H_ + c0;
  float f[32];
#pragma unroll
  for (int q = 0; q < 8; ++q) {
    float4v v = *(const float4v*)(p + q * 4);
    f[q * 4 + 0] = v[0]; f[q * 4 + 1] = v[1]; f[q * 4 + 2] = v[2]; f[q * 4 + 3] = v[3];
  }
  float s = 0.f, ss = 0.f;
#pragma unroll
  for (int i = 0; i < 32; ++i) { s += f[i]; ss += f[i] * f[i]; }
#pragma unroll
  for (int m = 1; m <= 16; m <<= 1) { s += __shfl_xor(s, m, 64); ss += __shfl_xor(ss, m, 64); }
  float mu = s * (1.f / H_);
  float var = ss * (1.f / H_) - mu * mu;
  float rs = rsqrtf(var + LNEPS);
  // permuted LN-param layout: logical 32k+c stored at 32k+((c+k)&31) -> conflict-free
#pragma unroll
  for (int c = 0; c < 32; ++c) {
    float w = lnw[c0 + ((c + k) & 31)];
    float b = lnb[c0 + ((c + k) & 31)];
    f[c] = tanh_fast((f[c] - mu) * rs * w + b);
  }
  if (wr && k == cg) {
    float* pa = gA + (size_t)r * H_ + c0;
#pragma unroll
    for (int q = 0; q < 8; ++q) *(float4v*)(pa + q * 4) = *(const float4v*)&f[q * 4];
    if (gB) {
      float* pb = gB + (size_t)r * H_ + c0;
#pragma unroll
      for (int q = 0; q < 8; ++q) *(float4v*)(pb + q * 4) = *(const float4v*)&f[q * 4];
    }
  }
#pragma unroll
  for (int q = 0; q < 4; ++q) {
    h16x8 h;
#pragma unroll
    for (int j = 0; j < 8; ++j) h[j] = (_Float16)f[q * 8 + j];
    *(h16x8*)&dA[chix(r, c0 + q * 8)] = h;
  }
}

#define MFMA(a, b, c) __builtin_amdgcn_mfma_f32_16x16x32_f16(a, b, c, 0, 0, 0)
#define AF(idx) (*(const h16x8*)&sA[chix(lane & 15, (idx) + kb8)])

// geometry: 256 blocks = layer(2) x rg(4) x cg(32); block = 32 cols x 16 rows;
// 512 thr = 8 waves = 2 colt x 4 kh
__global__ __launch_bounds__(512, 1) void rnn_persist(
    const float* __restrict__ input, const float* __restrict__ hidden,
    const float* __restrict__ W_ih0, const float* __restrict__ W_hh0,
    const float* __restrict__ b_ih0, const float* __restrict__ b_hh0,
    const float* __restrict__ ln_w0, const float* __restrict__ ln_b0,
    const float* __restrict__ W_ih1, const float* __restrict__ W_hh1,
    const float* __restrict__ b_ih1, const float* __restrict__ b_hh1,
    const float* __restrict__ ln_w1, const float* __restrict__ ln_b1,
    float* gout, float* pre0, float* pre1,
    ushort_t* flag0a, ushort_t* flag0b, ushort_t* flag1a) {
  __shared__ ushort_t sA[16 * 1032];
  __shared__ float slnw0[1024], slnb0[1024];
  __shared__ float slnw1[1024], slnb1[1024];
  __shared__ float sacc[3][2][16][16];

  const int tid = threadIdx.x;
  const int lane = tid & 63;
  const int w = tid >> 6;
  const int colt = w & 1, kh = w >> 1;  // 2 col-tiles x 4 K-quarters
  const int blk = blockIdx.x;
  const int layer = blk >> 7;
  const int id = blk & 127;
  const int rg = id >> 5, cg = id & 31;
  const int rowbase = rg * RB;
  const int cgl = cg * 32 + colt * 16 + (lane & 15);
  const int kb8 = (lane >> 4) * 8;
  const int l15 = lane & 15;

  for (int i = tid; i < H_; i += 512) {
    int pi = (i & ~31) | ((i + (i >> 5)) & 31);
    slnw0[pi] = ln_w0[i]; slnb0[pi] = ln_b0[i];
    slnw1[pi] = ln_w1[i]; slnb1[pi] = ln_b1[i];
  }

  float bias = 0.f;

  if (layer == 0) {
    // per-wave weights: W_ih0 K=128 slice (4 frags, 16 VGPR) + W_hh0 K=256 slice (8, 32 VGPR)
    h16x8 WX[4], WH[8];
#pragma unroll
    for (int s = 0; s < 4; ++s) {
      WX[s] = ldw8h(W_ih0 + (size_t)cgl * IN_ + kh * 128 + s * 32 + kb8);
      PIN8(WX[s]);
    }
#pragma unroll
    for (int s = 0; s < 8; ++s) {
      WH[s] = ldw8h(W_hh0 + (size_t)cgl * H_ + kh * 256 + s * 32 + kb8);
      PIN8(WH[s]);
    }
    if (kh == 0) bias = b_ih0[cgl] + b_hh0[cgl];
    __syncthreads();

    for (int t = 0; t < T_; ++t) {
      stageXh(input + ((size_t)t * B_ + rowbase) * IN_, sA, tid);
      __syncthreads();
      f32x4 acc = (kh == 0) ? (f32x4){bias, bias, bias, bias} : (f32x4){0.f, 0.f, 0.f, 0.f};
#pragma unroll
      for (int s = 0; s < 4; ++s) acc = MFMA(AF(kh * 128 + s * 32), WX[s], acc);
      if (tid == 0 && t > 0) poll32h(&flag0a[FL(t - 1, rg)], t);
      __syncthreads();
      if (t == 0) stageHf(hidden + (size_t)rowbase * H_, sA, tid);
      else stageLTh(pre0 + ((size_t)(t - 1) * B_ + rowbase) * H_, sA,
                    slnw0, slnb0, tid, cg, false, nullptr, nullptr);
      __syncthreads();
#pragma unroll
      for (int s = 0; s < 8; ++s) acc = MFMA(AF(kh * 256 + s * 32), WH[s], acc);
      if (kh > 0) {
#pragma unroll
        for (int j = 0; j < 4; ++j) sacc[kh - 1][colt][(lane >> 4) * 4 + j][l15] = acc[j];
      }
      __syncthreads();
      if (kh == 0) {
        float* dst = pre0 + ((size_t)t * B_ + rowbase) * H_;
#pragma unroll
        for (int j = 0; j < 4; ++j) {
          int row = (lane >> 4) * 4 + j;
          float v = acc[j] + sacc[0][colt][row][l15] + sacc[1][colt][row][l15] +
                    sacc[2][colt][row][l15];
          st1_sys(&dst[(size_t)row * H_ + cgl], v);
        }
        relfence();
      }
      __syncthreads();
      if (tid == 0) {
        stamp16(&flag0a[FL(t, rg) + cg], t + 1);  // line for L0 pollers
        stamp16(&flag0b[FL(t, rg) + cg], t + 1);  // replica for L1 pollers
      }
    }
    // epilogue: h_fin[0] slice
    if (tid == 0) poll32h(&flag0a[FL(T_ - 1, rg)], T_);
    __syncthreads();
    stageLTh(pre0 + ((size_t)(T_ - 1) * B_ + rowbase) * H_, sA, slnw0, slnb0, tid, cg, true,
             gout + (size_t)T_ * B_ * H_ + (size_t)rowbase * H_, nullptr);
  } else {
    // per-wave weights: W_ih1 + W_hh1 K=256 slices (8+8 frags) = 64 VGPR
    h16x8 WB[8], WA[8];
#pragma unroll
    for (int s = 0; s < 8; ++s) {
      WB[s] = ldw8h(W_ih1 + (size_t)cgl * H_ + kh * 256 + s * 32 + kb8);
      PIN8(WB[s]);
    }
#pragma unroll
    for (int s = 0; s < 8; ++s) {
      WA[s] = ldw8h(W_hh1 + (size_t)cgl * H_ + kh * 256 + s * 32 + kb8);
      PIN8(WA[s]);
    }
    if (kh == 0) bias = b_ih1[cgl] + b_hh1[cgl];
    __syncthreads();

    for (int t = 0; t < T_; ++t) {
      if (tid == 0) poll32h(&flag0b[FL(t, rg)], t + 1);  // h0[t] ready (L0 runs ahead)
      __syncthreads();
      stageLTh(pre0 + ((size_t)t * B_ + rowbase) * H_, sA,
               slnw0, slnb0, tid, cg, false, nullptr, nullptr);
      __syncthreads();
      f32x4 acc = (kh == 0) ? (f32x4){bias, bias, bias, bias} : (f32x4){0.f, 0.f, 0.f, 0.f};
#pragma unroll
      for (int s = 0; s < 8; ++s) acc = MFMA(AF(kh * 256 + s * 32), WB[s], acc);
      if (tid == 0 && t > 0) poll32h(&flag1a[FL(t - 1, rg)], t);  // own-layer chain
      __syncthreads();
      if (t == 0) stageHf(hidden + (size_t)B_ * H_ + (size_t)rowbase * H_, sA, tid);
      else stageLTh(pre1 + ((size_t)(t - 1) * B_ + rowbase) * H_, sA,
                    slnw1, slnb1, tid, cg, true,
                    gout + ((size_t)(t - 1) * B_ + rowbase) * H_, nullptr);
      __syncthreads();
#pragma unroll
      for (int s = 0; s < 8; ++s) acc = MFMA(AF(kh * 256 + s * 32), WA[s], acc);
      if (kh > 0) {
#pragma unroll
        for (int j = 0; j < 4; ++j) sacc[kh - 1][colt][(lane >> 4) * 4 + j][l15] = acc[j];
      }
      __syncthreads();
      if (kh == 0) {
        float* dst = pre1 + ((size_t)t * B_ + rowbase) * H_;
#pragma unroll
        for (int j = 0; j < 4; ++j) {
          int row = (lane >> 4) * 4 + j;
          float v = acc[j] + sacc[0][colt][row][l15] + sacc[1][colt][row][l15] +
                    sacc[2][colt][row][l15];
          st1_sys(&dst[(size_t)row * H_ + cgl], v);
        }
        relfence();
      }
      __syncthreads();
      if (tid == 0) stamp16(&flag1a[FL(t, rg) + cg], t + 1);
    }
    // epilogue: gout[T-1] + h_fin[1] slices
    if (tid == 0) poll32h(&flag1a[FL(T_ - 1, rg)], T_);
    __syncthreads();
    stageLTh(pre1 + ((size_t)(T_ - 1) * B_ + rowbase) * H_, sA, slnw1, slnb1, tid, cg, true,
             gout + ((size_t)(T_ - 1) * B_ + rowbase) * H_,
             gout + (size_t)T_ * B_ * H_ + (size_t)B_ * H_ + (size_t)rowbase * H_);
  }
}

extern "C" void kernel_launch(void* const* d_in, const int* in_sizes, int n_in,
                              void* d_out, int out_size, void* d_ws, size_t ws_size,
                              hipStream_t stream) {
  const float* input = (const float*)d_in[0];
  const float* hidden = (const float*)d_in[1];
  const float* W_ih0 = (const float*)d_in[2];
  const float* W_hh0 = (const float*)d_in[3];
  const float* b_ih0 = (const float*)d_in[4];
  const float* b_hh0 = (const float*)d_in[5];
  const float* ln_w0 = (const float*)d_in[6];
  const float* ln_b0 = (const float*)d_in[7];
  const float* W_ih1 = (const float*)d_in[8];
  const float* W_hh1 = (const float*)d_in[9];
  const float* b_ih1 = (const float*)d_in[10];
  const float* b_hh1 = (const float*)d_in[11];
  const float* ln_w1 = (const float*)d_in[12];
  const float* ln_b1 = (const float*)d_in[13];
  float* gout = (float*)d_out;

  const size_t slabT = (size_t)T_ * B_ * H_ * 4;  // 128 MB per no-wrap buffer
  char* ws = (char*)d_ws;
  float* pre0 = (float*)ws;
  float* pre1 = (float*)(ws + slabT);
  char* ctrl = ws + 2 * slabT;
  ushort_t* flag0a = (ushort_t*)ctrl;                  // 2048 lines x 64B = 128 KB
  ushort_t* flag0b = (ushort_t*)(ctrl + 0x20000);      // 128 KB
  ushort_t* flag1a = (ushort_t*)(ctrl + 0x40000);      // 128 KB

  (void)hipMemsetAsync(ctrl, 0, 0x60000, stream);
  hipLaunchKernelGGL(rnn_persist, dim3(256), dim3(512), 0, stream,
                     input, hidden, W_ih0, W_hh0, b_ih0, b_hh0, ln_w0, ln_b0,
                     W_ih1, W_hh1, b_ih1, b_hh1, ln_w1, ln_b1,
                     gout, pre0, pre1, flag0a, flag0b, flag1a);
}

// Round 11
// 5087.518 us; speedup vs baseline: 7.9516x; 1.3367x over previous
//
#include <hip/hip_runtime.h>
#include <stdint.h>

#define T_ 512
#define B_ 64
#define IN_ 512
#define H_ 1024
#define RB 16
#define LNEPS 1e-5f
#define FL(t, rg) (((t) * 4 + (rg)) * 32)  // ushort index: 64B line, 32 u16 stamps

typedef __attribute__((ext_vector_type(8))) _Float16 h16x8;
typedef __attribute__((ext_vector_type(4))) float f32x4;
typedef __attribute__((ext_vector_type(4))) float float4v;
typedef __attribute__((ext_vector_type(4))) int int4v;
typedef unsigned short ushort_t;

__device__ __forceinline__ float tanh_fast(float y) {
  y = fminf(15.f, fmaxf(-15.f, y));
  float e = __expf(2.f * y);
  float r;
  asm("v_rcp_f32 %0, %1" : "=v"(r) : "v"(e + 1.f));
  return __builtin_fmaf(-2.f, r, 1.f);  // tanh = 1 - 2/(e^2y+1)
}
__device__ __forceinline__ h16x8 ldw8h(const float* p) {
  float4v a = *(const float4v*)p;
  float4v b = *(const float4v*)(p + 4);
  h16x8 o;
  o[0] = (_Float16)a[0]; o[1] = (_Float16)a[1]; o[2] = (_Float16)a[2]; o[3] = (_Float16)a[3];
  o[4] = (_Float16)b[0]; o[5] = (_Float16)b[1]; o[6] = (_Float16)b[2]; o[7] = (_Float16)b[3];
  return o;
}
#define PIN8(x) asm volatile("" : "+v"(x))

// ---- L3-direct (sc0 sc1) stores + u16 stamp/poll sync (no RMW, no cache-wide ops) ----
__device__ __forceinline__ void sth_sys(ushort_t* p, float v) {
  _Float16 h = (_Float16)v;
  int s = (int)__builtin_bit_cast(short, h);
  asm volatile("global_store_short %0, %1, off sc0 sc1" :: "v"(p), "v"(s) : "memory");
}
__device__ __forceinline__ void relfence() { asm volatile("s_waitcnt vmcnt(0)" ::: "memory"); }
__device__ __forceinline__ void stamp16(ushort_t* p, int v) {
  asm volatile("global_store_short %0, %1, off sc0 sc1" :: "v"(p), "v"(v) : "memory");
}
// poll one 64B line (32 u16 stamps) until min >= target
__device__ __forceinline__ void poll32h(const ushort_t* p, int target) {
  int n = 0;
  while (true) {
    int4v a, b, c, d;
    asm volatile(
        "global_load_dwordx4 %0, %4, off sc0 sc1\n\t"
        "global_load_dwordx4 %1, %4, off offset:16 sc0 sc1\n\t"
        "global_load_dwordx4 %2, %4, off offset:32 sc0 sc1\n\t"
        "global_load_dwordx4 %3, %4, off offset:48 sc0 sc1\n\t"
        "s_waitcnt vmcnt(0)"
        : "=&v"(a), "=&v"(b), "=&v"(c), "=&v"(d) : "v"(p) : "memory");
    int mn = 0xFFFF;
#pragma unroll
    for (int i = 0; i < 4; ++i) {
      unsigned u0 = (unsigned)a[i], u1 = (unsigned)b[i], u2 = (unsigned)c[i], u3 = (unsigned)d[i];
      mn = min(mn, (int)(u0 & 0xFFFFu)); mn = min(mn, (int)(u0 >> 16));
      mn = min(mn, (int)(u1 & 0xFFFFu)); mn = min(mn, (int)(u1 >> 16));
      mn = min(mn, (int)(u2 & 0xFFFFu)); mn = min(mn, (int)(u2 >> 16));
      mn = min(mn, (int)(u3 & 0xFFFFu)); mn = min(mn, (int)(u3 >> 16));
    }
    if (mn >= target) return;
    if (n < 4) __builtin_amdgcn_s_sleep(1);
    else __builtin_amdgcn_s_sleep(4);
    if (++n > 2000000) return;  // safety: wrong data instead of hang
  }
}

// LDS swizzle (half units): chunk = 8 halves (16B); fold row/owner bits into bank bits
__device__ __forceinline__ int chix(int r, int c) {
  int ch = c >> 3;
  int low = (ch ^ r ^ (ch >> 2)) & 3;
  return r * 1032 + ((((ch >> 2) << 2) | low) << 3) + (c & 7);
}

// ---- staging: 512 threads; r=tid>>5 in 0..15, k=tid&31 owns cols [32k,32k+32) ----
__device__ __forceinline__ void stageHf(const float* src, ushort_t* dA, int tid) {
  int r = tid >> 5, k = tid & 31, c0 = k * 32;
  const float* p = src + (size_t)r * H_ + c0;
#pragma unroll
  for (int q = 0; q < 4; ++q) {
    float4v a = *(const float4v*)(p + q * 8);
    float4v b = *(const float4v*)(p + q * 8 + 4);
    h16x8 h;
    h[0] = (_Float16)a[0]; h[1] = (_Float16)a[1]; h[2] = (_Float16)a[2]; h[3] = (_Float16)a[3];
    h[4] = (_Float16)b[0]; h[5] = (_Float16)b[1]; h[6] = (_Float16)b[2]; h[7] = (_Float16)b[3];
    *(h16x8*)&dA[chix(r, c0 + q * 8)] = h;
  }
}
__device__ __forceinline__ void stageXh(const float* src, ushort_t* dA, int tid) {
  int r = tid >> 5, k = tid & 31, c0 = k * 16;
  const float* p = src + (size_t)r * IN_ + c0;
#pragma unroll
  for (int q = 0; q < 2; ++q) {
    float4v a = *(const float4v*)(p + q * 8);
    float4v b = *(const float4v*)(p + q * 8 + 4);
    h16x8 h;
    h[0] = (_Float16)a[0]; h[1] = (_Float16)a[1]; h[2] = (_Float16)a[2]; h[3] = (_Float16)a[3];
    h[4] = (_Float16)b[0]; h[5] = (_Float16)b[1]; h[6] = (_Float16)b[2]; h[7] = (_Float16)b[3];
    *(h16x8*)&dA[chix(r, c0 + q * 8)] = h;
  }
}
// fp16 pre rows (plain loads; write-once addresses) -> LN+tanh -> fp16 LDS;
// if wr, thread k==cg writes its fp32 cols [32cg,32cg+32) to gA (and gB)
__device__ __forceinline__ void stageLTh(const ushort_t* src, ushort_t* dA,
                                         const float* lnw, const float* lnb, int tid,
                                         int cg, bool wr, float* gA, float* gB) {
  int r = tid >> 5, k = tid & 31, c0 = k * 32;
  const ushort_t* p = src + (size_t)r * H_ + c0;
  float f[32];
#pragma unroll
  for (int q = 0; q < 4; ++q) {
    h16x8 hv = *(const h16x8*)(p + q * 8);
#pragma unroll
    for (int j = 0; j < 8; ++j) f[q * 8 + j] = (float)hv[j];
  }
  float s = 0.f, ss = 0.f;
#pragma unroll
  for (int i = 0; i < 32; ++i) { s += f[i]; ss += f[i] * f[i]; }
#pragma unroll
  for (int m = 1; m <= 16; m <<= 1) { s += __shfl_xor(s, m, 64); ss += __shfl_xor(ss, m, 64); }
  float mu = s * (1.f / H_);
  float var = ss * (1.f / H_) - mu * mu;
  float rs = rsqrtf(var + LNEPS);
  // permuted LN-param layout: logical 32k+c stored at 32k+((c+k)&31) -> conflict-free
#pragma unroll
  for (int c = 0; c < 32; ++c) {
    float w = lnw[c0 + ((c + k) & 31)];
    float b = lnb[c0 + ((c + k) & 31)];
    f[c] = tanh_fast((f[c] - mu) * rs * w + b);
  }
  if (wr && k == cg) {
    float* pa = gA + (size_t)r * H_ + c0;
#pragma unroll
    for (int q = 0; q < 8; ++q) *(float4v*)(pa + q * 4) = *(const float4v*)&f[q * 4];
    if (gB) {
      float* pb = gB + (size_t)r * H_ + c0;
#pragma unroll
      for (int q = 0; q < 8; ++q) *(float4v*)(pb + q * 4) = *(const float4v*)&f[q * 4];
    }
  }
#pragma unroll
  for (int q = 0; q < 4; ++q) {
    h16x8 h;
#pragma unroll
    for (int j = 0; j < 8; ++j) h[j] = (_Float16)f[q * 8 + j];
    *(h16x8*)&dA[chix(r, c0 + q * 8)] = h;
  }
}

#define MFMA(a, b, c) __builtin_amdgcn_mfma_f32_16x16x32_f16(a, b, c, 0, 0, 0)
#define AF(idx) (*(const h16x8*)&sA[chix(lane & 15, (idx) + kb8)])

// geometry: 256 blocks; XCD-pinned mapping: layer=(blk>>2)&1, rg=blk&3, cg=blk>>3
// -> all 32 cg blocks of one (layer,rg) share an XCD (round-robin dispatch) -> L2 dedup
__global__ __launch_bounds__(512, 1) void rnn_persist(
    const float* __restrict__ input, const float* __restrict__ hidden,
    const float* __restrict__ W_ih0, const float* __restrict__ W_hh0,
    const float* __restrict__ b_ih0, const float* __restrict__ b_hh0,
    const float* __restrict__ ln_w0, const float* __restrict__ ln_b0,
    const float* __restrict__ W_ih1, const float* __restrict__ W_hh1,
    const float* __restrict__ b_ih1, const float* __restrict__ b_hh1,
    const float* __restrict__ ln_w1, const float* __restrict__ ln_b1,
    float* gout, ushort_t* pre0, ushort_t* pre1,
    ushort_t* flag0a, ushort_t* flag0b, ushort_t* flag1a) {
  __shared__ ushort_t sA[16 * 1032];
  __shared__ float slnw0[1024], slnb0[1024];
  __shared__ float slnw1[1024], slnb1[1024];
  __shared__ float sacc[3][2][16][16];

  const int tid = threadIdx.x;
  const int lane = tid & 63;
  const int w = tid >> 6;
  const int colt = w & 1, kh = w >> 1;  // 2 col-tiles x 4 K-quarters
  const int blk = blockIdx.x;
  const int layer = (blk >> 2) & 1;
  const int rg = blk & 3;
  const int cg = blk >> 3;
  const int rowbase = rg * RB;
  const int cgl = cg * 32 + colt * 16 + (lane & 15);
  const int kb8 = (lane >> 4) * 8;
  const int l15 = lane & 15;

  for (int i = tid; i < H_; i += 512) {
    int pi = (i & ~31) | ((i + (i >> 5)) & 31);
    slnw0[pi] = ln_w0[i]; slnb0[pi] = ln_b0[i];
    slnw1[pi] = ln_w1[i]; slnb1[pi] = ln_b1[i];
  }

  float bias = 0.f;

  if (layer == 0) {
    // per-wave weights: W_ih0 K=128 slice (4 frags) + W_hh0 K=256 slice (8 frags)
    h16x8 WX[4], WH[8];
#pragma unroll
    for (int s = 0; s < 4; ++s) {
      WX[s] = ldw8h(W_ih0 + (size_t)cgl * IN_ + kh * 128 + s * 32 + kb8);
      PIN8(WX[s]);
    }
#pragma unroll
    for (int s = 0; s < 8; ++s) {
      WH[s] = ldw8h(W_hh0 + (size_t)cgl * H_ + kh * 256 + s * 32 + kb8);
      PIN8(WH[s]);
    }
    if (kh == 0) bias = b_ih0[cgl] + b_hh0[cgl];
    __syncthreads();

    for (int t = 0; t < T_; ++t) {
      stageXh(input + ((size_t)t * B_ + rowbase) * IN_, sA, tid);
      __syncthreads();
      f32x4 acc = (kh == 0) ? (f32x4){bias, bias, bias, bias} : (f32x4){0.f, 0.f, 0.f, 0.f};
#pragma unroll
      for (int s = 0; s < 4; ++s) acc = MFMA(AF(kh * 128 + s * 32), WX[s], acc);
      if (tid == 0 && t > 0) poll32h(&flag0a[FL(t - 1, rg)], t);
      __syncthreads();
      if (t == 0) stageHf(hidden + (size_t)rowbase * H_, sA, tid);
      else stageLTh(pre0 + ((size_t)(t - 1) * B_ + rowbase) * H_, sA,
                    slnw0, slnb0, tid, cg, false, nullptr, nullptr);
      __syncthreads();
#pragma unroll
      for (int s = 0; s < 8; ++s) acc = MFMA(AF(kh * 256 + s * 32), WH[s], acc);
      if (kh > 0) {
#pragma unroll
        for (int j = 0; j < 4; ++j) sacc[kh - 1][colt][(lane >> 4) * 4 + j][l15] = acc[j];
      }
      __syncthreads();
      if (kh == 0) {
        ushort_t* dst = pre0 + ((size_t)t * B_ + rowbase) * H_;
#pragma unroll
        for (int j = 0; j < 4; ++j) {
          int row = (lane >> 4) * 4 + j;
          float v = acc[j] + sacc[0][colt][row][l15] + sacc[1][colt][row][l15] +
                    sacc[2][colt][row][l15];
          sth_sys(&dst[(size_t)row * H_ + cgl], v);
        }
        relfence();
      }
      __syncthreads();
      if (tid == 0) {
        stamp16(&flag0a[FL(t, rg) + cg], t + 1);  // line for L0 pollers
        stamp16(&flag0b[FL(t, rg) + cg], t + 1);  // replica for L1 pollers
      }
    }
    // epilogue: h_fin[0] slice
    if (tid == 0) poll32h(&flag0a[FL(T_ - 1, rg)], T_);
    __syncthreads();
    stageLTh(pre0 + ((size_t)(T_ - 1) * B_ + rowbase) * H_, sA, slnw0, slnb0, tid, cg, true,
             gout + (size_t)T_ * B_ * H_ + (size_t)rowbase * H_, nullptr);
  } else {
    // per-wave weights: W_ih1 + W_hh1 K=256 slices (8+8 frags)
    h16x8 WB[8], WA[8];
#pragma unroll
    for (int s = 0; s < 8; ++s) {
      WB[s] = ldw8h(W_ih1 + (size_t)cgl * H_ + kh * 256 + s * 32 + kb8);
      PIN8(WB[s]);
    }
#pragma unroll
    for (int s = 0; s < 8; ++s) {
      WA[s] = ldw8h(W_hh1 + (size_t)cgl * H_ + kh * 256 + s * 32 + kb8);
      PIN8(WA[s]);
    }
    if (kh == 0) bias = b_ih1[cgl] + b_hh1[cgl];
    __syncthreads();

    for (int t = 0; t < T_; ++t) {
      if (tid == 0) poll32h(&flag0b[FL(t, rg)], t + 1);  // h0[t] ready (L0 runs ahead)
      __syncthreads();
      stageLTh(pre0 + ((size_t)t * B_ + rowbase) * H_, sA,
               slnw0, slnb0, tid, cg, false, nullptr, nullptr);
      __syncthreads();
      f32x4 acc = (kh == 0) ? (f32x4){bias, bias, bias, bias} : (f32x4){0.f, 0.f, 0.f, 0.f};
#pragma unroll
      for (int s = 0; s < 8; ++s) acc = MFMA(AF(kh * 256 + s * 32), WB[s], acc);
      if (tid == 0 && t > 0) poll32h(&flag1a[FL(t - 1, rg)], t);  // own-layer chain
      __syncthreads();
      if (t == 0) stageHf(hidden + (size_t)B_ * H_ + (size_t)rowbase * H_, sA, tid);
      else stageLTh(pre1 + ((size_t)(t - 1) * B_ + rowbase) * H_, sA,
                    slnw1, slnb1, tid, cg, true,
                    gout + ((size_t)(t - 1) * B_ + rowbase) * H_, nullptr);
      __syncthreads();
#pragma unroll
      for (int s = 0; s < 8; ++s) acc = MFMA(AF(kh * 256 + s * 32), WA[s], acc);
      if (kh > 0) {
#pragma unroll
        for (int j = 0; j < 4; ++j) sacc[kh - 1][colt][(lane >> 4) * 4 + j][l15] = acc[j];
      }
      __syncthreads();
      if (kh == 0) {
        ushort_t* dst = pre1 + ((size_t)t * B_ + rowbase) * H_;
#pragma unroll
        for (int j = 0; j < 4; ++j) {
          int row = (lane >> 4) * 4 + j;
          float v = acc[j] + sacc[0][colt][row][l15] + sacc[1][colt][row][l15] +
                    sacc[2][colt][row][l15];
          sth_sys(&dst[(size_t)row * H_ + cgl], v);
        }
        relfence();
      }
      __syncthreads();
      if (tid == 0) stamp16(&flag1a[FL(t, rg) + cg], t + 1);
    }
    // epilogue: gout[T-1] + h_fin[1] slices
    if (tid == 0) poll32h(&flag1a[FL(T_ - 1, rg)], T_);
    __syncthreads();
    stageLTh(pre1 + ((size_t)(T_ - 1) * B_ + rowbase) * H_, sA, slnw1, slnb1, tid, cg, true,
             gout + ((size_t)(T_ - 1) * B_ + rowbase) * H_,
             gout + (size_t)T_ * B_ * H_ + (size_t)B_ * H_ + (size_t)rowbase * H_);
  }
}

extern "C" void kernel_launch(void* const* d_in, const int* in_sizes, int n_in,
                              void* d_out, int out_size, void* d_ws, size_t ws_size,
                              hipStream_t stream) {
  const float* input = (const float*)d_in[0];
  const float* hidden = (const float*)d_in[1];
  const float* W_ih0 = (const float*)d_in[2];
  const float* W_hh0 = (const float*)d_in[3];
  const float* b_ih0 = (const float*)d_in[4];
  const float* b_hh0 = (const float*)d_in[5];
  const float* ln_w0 = (const float*)d_in[6];
  const float* ln_b0 = (const float*)d_in[7];
  const float* W_ih1 = (const float*)d_in[8];
  const float* W_hh1 = (const float*)d_in[9];
  const float* b_ih1 = (const float*)d_in[10];
  const float* b_hh1 = (const float*)d_in[11];
  const float* ln_w1 = (const float*)d_in[12];
  const float* ln_b1 = (const float*)d_in[13];
  float* gout = (float*)d_out;

  const size_t slabT = (size_t)T_ * B_ * H_ * 2;  // 64 MB per no-wrap fp16 buffer
  char* ws = (char*)d_ws;
  ushort_t* pre0 = (ushort_t*)ws;
  ushort_t* pre1 = (ushort_t*)(ws + slabT);
  char* ctrl = ws + 2 * slabT;
  ushort_t* flag0a = (ushort_t*)ctrl;                  // 2048 lines x 64B = 128 KB
  ushort_t* flag0b = (ushort_t*)(ctrl + 0x20000);      // 128 KB
  ushort_t* flag1a = (ushort_t*)(ctrl + 0x40000);      // 128 KB

  (void)hipMemsetAsync(ctrl, 0, 0x60000, stream);
  hipLaunchKernelGGL(rnn_persist, dim3(256), dim3(512), 0, stream,
                     input, hidden, W_ih0, W_hh0, b_ih0, b_hh0, ln_w0, ln_b0,
                     W_ih1, W_hh1, b_ih1, b_hh1, ln_w1, ln_b1,
                     gout, pre0, pre1, flag0a, flag0b, flag1a);
}